// Round 10
// baseline (1721.556 us; speedup 1.0000x reference)
//
#include <hip/hip_runtime.h>
#include <hip/hip_bf16.h>
#include <hip/hip_fp16.h>

// N=100000 nodes, F_in=20, 4 heads x 16 ch = 64, E=3.2M edges (+N self loops),
// 256 graphs. All fp32 in/out.
//
// R9: csr_build existed only to let the gather walk per-dst lists. With
// 128-node buckets the whole per-bucket accumulator (128 x (64ch + 4z) fp32
// = 34.8KB) fits in LDS -> aggregate straight from the UNSORTED bucket lists:
// one wave per edge covers all 64 channels (xh read = one coalesced 128B wave
// load; ds_add to 64 consecutive addrs = conflict-free). Deletes csr_build,
// srcs, off. Self-loops + z-normalize + bias fold into the block epilogue.
#define FIN 20
#define HEADS 4
#define F 64
#define NEG_SLOPE 0.2f
#define AP 68        // mlp activation row stride (floats)
#define BSHIFT 7     // 128 nodes per bucket
#define BMASK 127
#define BNODES 128
#define BCAP 4608    // per-bucket edge capacity (mean 4096, +8 sigma)
#define NB_MAX 800   // >= nbuck = 782
#define ACC_W 68     // accum row: 64 channels + 4 z
#define BIN_EPT 16   // edges per thread in bin pass

// ---------------------------------------------------------------------------
// Fused kernel 1: blocks [0, nbP) do node_prep; blocks [nbP, nbP+nbB) bin
// edges by dst bucket (LDS count -> one global reservation per bucket ->
// packed (dstlocal<<17 | src) words in contiguous runs).
// ---------------------------------------------------------------------------
__global__ void __launch_bounds__(256)
prep_bin(const float* __restrict__ x,
         const float* __restrict__ w_gat,
         const float* __restrict__ att_src,
         const float* __restrict__ att_dst,
         __half* __restrict__ xh,
         float* __restrict__ a_s,
         float* __restrict__ a_d,
         const int* __restrict__ ei, int E, int nbuck,
         int* __restrict__ gcount, int* __restrict__ bucketData,
         int n_nodes, int nbP)
{
    if (blockIdx.x < nbP) {
        // ---------------- node_prep ----------------
        __shared__ __align__(16) float w[FIN * F];
        __shared__ float asrc[F];
        __shared__ float adst[F];
        for (int i = threadIdx.x; i < FIN * F; i += 256) w[i] = w_gat[i];
        if (threadIdx.x < F) {
            asrc[threadIdx.x] = att_src[threadIdx.x];
            adst[threadIdx.x] = att_dst[threadIdx.x];
        }
        __syncthreads();

        int n = blockIdx.x * 256 + threadIdx.x;
        if (n >= n_nodes) return;

        float xv[FIN];
#pragma unroll
        for (int q = 0; q < FIN / 4; ++q) {
            float4 x4 = *(const float4*)&x[(size_t)n * FIN + q * 4];
            xv[q * 4 + 0] = x4.x; xv[q * 4 + 1] = x4.y;
            xv[q * 4 + 2] = x4.z; xv[q * 4 + 3] = x4.w;
        }

        float as[HEADS] = {0.f, 0.f, 0.f, 0.f};
        float ad[HEADS] = {0.f, 0.f, 0.f, 0.f};

#pragma unroll
        for (int j4 = 0; j4 < F / 4; ++j4) {
            float4 acc = make_float4(0.f, 0.f, 0.f, 0.f);
#pragma unroll
            for (int k = 0; k < FIN; ++k) {
                float4 w4 = *(const float4*)&w[k * F + j4 * 4];
                acc.x += xv[k] * w4.x;
                acc.y += xv[k] * w4.y;
                acc.z += xv[k] * w4.z;
                acc.w += xv[k] * w4.w;
            }
            __half2 p0 = __floats2half2_rn(acc.x, acc.y);
            __half2 p1 = __floats2half2_rn(acc.z, acc.w);
            float2 st;
            ((__half2*)&st)[0] = p0;
            ((__half2*)&st)[1] = p1;
            *(float2*)&xh[(size_t)n * F + j4 * 4] = st;

            int h = j4 >> 2;
            int jb = j4 * 4;
            as[h] += acc.x * asrc[jb] + acc.y * asrc[jb + 1] + acc.z * asrc[jb + 2] + acc.w * asrc[jb + 3];
            ad[h] += acc.x * adst[jb] + acc.y * adst[jb + 1] + acc.z * adst[jb + 2] + acc.w * adst[jb + 3];
        }
#pragma unroll
        for (int h = 0; h < HEADS; ++h) {
            a_s[(size_t)n * HEADS + h] = as[h];
            a_d[(size_t)n * HEADS + h] = ad[h];
        }
    } else {
        // ---------------- bin_pass ----------------
        __shared__ int lcnt[NB_MAX];
        __shared__ int lbase[NB_MAX];
        for (int i = threadIdx.x; i < nbuck; i += 256) lcnt[i] = 0;
        __syncthreads();

        int base = (blockIdx.x - nbP) * (256 * BIN_EPT);
        int b_[BIN_EPT], w_[BIN_EPT];
#pragma unroll
        for (int j = 0; j < BIN_EPT; ++j) {
            int e = base + j * 256 + threadIdx.x;
            if (e < E) {
                int src = ei[e];
                int dst = ei[E + e];
                b_[j] = dst >> BSHIFT;
                w_[j] = ((dst & BMASK) << 17) | src;   // src < 2^17 (N=100000)
                atomicAdd(&lcnt[b_[j]], 1);
            } else b_[j] = -1;
        }
        __syncthreads();
        for (int i = threadIdx.x; i < nbuck; i += 256) {
            int c = lcnt[i];
            lbase[i] = c ? atomicAdd(&gcount[i], c) : 0;
            lcnt[i] = 0;
        }
        __syncthreads();
#pragma unroll
        for (int j = 0; j < BIN_EPT; ++j) {
            if (b_[j] >= 0) {
                int p = lbase[b_[j]] + atomicAdd(&lcnt[b_[j]], 1);
                if (p < BCAP) bucketData[(size_t)b_[j] * BCAP + p] = w_[j];
            }
        }
    }
}

// ---------------------------------------------------------------------------
// Bucket aggregation: one block per 128-node bucket. LDS accumulator
// [128][68] (64 ch + 4 z). One WAVE processes one edge across all 64
// channels: xh[src] is a single coalesced 128B wave load; ds_add hits 64
// consecutive addresses (conflict-free). Edges shfl-broadcast from 64-word
// register chunks. Epilogue adds the self loop, normalizes, adds bias,
// writes h0 coalesced.
// ---------------------------------------------------------------------------
__global__ void __launch_bounds__(256)
bucket_agg(const int* __restrict__ bucketData,
           const int* __restrict__ gcount,
           const float* __restrict__ a_s,
           const float* __restrict__ a_d,
           const __half* __restrict__ xh,
           const float* __restrict__ b_gat,
           float* __restrict__ h0out,
           int n_nodes)
{
    __shared__ float accum[BNODES * ACC_W];   // 34.8 KB
    __shared__ float s_ad[BNODES * HEADS];    // dst-side attn, 2 KB

    const int b = blockIdx.x;
    const int node0 = b << BSHIFT;
    const int wave = threadIdx.x >> 6;
    const int lane = threadIdx.x & 63;
    const int h = lane >> 4;

    for (int i = threadIdx.x; i < BNODES * ACC_W; i += 256) accum[i] = 0.f;
    for (int i = threadIdx.x; i < BNODES * HEADS; i += 256) {
        int n = node0 + (i >> 2);
        s_ad[i] = (n < n_nodes) ? a_d[(size_t)n * HEADS + (i & 3)] : 0.f;
    }
    __syncthreads();

    int cnt = gcount[b]; if (cnt > BCAP) cnt = BCAP;
    const int* bd = bucketData + (size_t)b * BCAP;

    // full 64-edge chunks, chunk c handled by wave c&3
    int nfull = cnt & ~63;
    for (int base = wave * 64; base < nfull; base += 256) {
        int my_w = bd[base + lane];
#pragma unroll 8
        for (int j = 0; j < 64; ++j) {
            int w = __shfl(my_w, j);
            int src = w & 0x1FFFF;
            int dl  = w >> 17;
            float l = a_s[(size_t)src * HEADS + h] + s_ad[dl * HEADS + h];
            l = fmaxf(l, NEG_SLOPE * l);                 // leaky relu
            float e = __expf(l);
            float xv = __half2float(xh[(size_t)src * F + lane]);
            atomicAdd(&accum[dl * ACC_W + lane], e * xv);
            if ((lane & 15) == 0) atomicAdd(&accum[dl * ACC_W + 64 + h], e);
        }
    }
    // tail chunk
    int rem = cnt - nfull;
    if (rem > 0 && wave == ((nfull >> 6) & 3)) {
        int my_w = bd[nfull + (lane < rem ? lane : rem - 1)];
        for (int j = 0; j < rem; ++j) {
            int w = __shfl(my_w, j);
            int src = w & 0x1FFFF;
            int dl  = w >> 17;
            float l = a_s[(size_t)src * HEADS + h] + s_ad[dl * HEADS + h];
            l = fmaxf(l, NEG_SLOPE * l);
            float e = __expf(l);
            float xv = __half2float(xh[(size_t)src * F + lane]);
            atomicAdd(&accum[dl * ACC_W + lane], e * xv);
            if ((lane & 15) == 0) atomicAdd(&accum[dl * ACC_W + 64 + h], e);
        }
    }
    __syncthreads();

    // epilogue: self loop + normalize + bias, coalesced h0 write
    float bg = b_gat[lane];
    for (int nl = wave; nl < BNODES; nl += 4) {
        int n = node0 + nl;
        if (n >= n_nodes) break;
        float l = a_s[(size_t)n * HEADS + h] + s_ad[nl * HEADS + h];
        l = fmaxf(l, NEG_SLOPE * l);
        float e = __expf(l);
        float xv = __half2float(xh[(size_t)n * F + lane]);
        float acc = accum[nl * ACC_W + lane] + e * xv;
        float z   = accum[nl * ACC_W + 64 + h] + e;
        h0out[(size_t)n * F + lane] = acc / z + bg;
    }
}

// ---------------------------------------------------------------------------
// MLP. 16 threads per node-PAIR (nodes n and n+16 of a 32-node block): each
// weight register load feeds both nodes' FMAs -> half the LDS weight traffic
// per node. Activations ping-pong through LDS (wave-synchronous).
// ---------------------------------------------------------------------------
__global__ void __launch_bounds__(256)
mlp_pool2(const float* __restrict__ h0g,
          const float* __restrict__ w_fuse, const float* __restrict__ b_fuse,
          const float* __restrict__ w_h1, const float* __restrict__ b_h1,
          const float* __restrict__ w_h2, const float* __restrict__ b_h2,
          const float* __restrict__ w_h3, const float* __restrict__ b_h3,
          float* __restrict__ rfeat,
          int n_nodes)
{
    __shared__ __align__(16) float wf[64 * 64];
    __shared__ __align__(16) float w1[64 * 32];
    __shared__ __align__(16) float w2[32 * 16];
    __shared__ __align__(16) float w3[16 * 16];
    __shared__ __align__(16) float bf[64];
    __shared__ __align__(16) float b1[32], b2[16], b3[16];
    __shared__ __align__(16) float actA[32 * AP];
    __shared__ __align__(16) float actB[32 * AP];

    for (int i = threadIdx.x; i < 64 * 64; i += 256) wf[i] = w_fuse[i];
    for (int i = threadIdx.x; i < 64 * 32; i += 256) w1[i] = w_h1[i];
    for (int i = threadIdx.x; i < 32 * 16; i += 256) w2[i] = w_h2[i];
    for (int i = threadIdx.x; i < 16 * 16; i += 256) w3[i] = w_h3[i];
    if (threadIdx.x < 64) bf[threadIdx.x] = b_fuse[threadIdx.x];
    else if (threadIdx.x < 96)  b1[threadIdx.x - 64] = b_h1[threadIdx.x - 64];
    else if (threadIdx.x < 112) b2[threadIdx.x - 96] = b_h2[threadIdx.x - 96];
    else if (threadIdx.x < 128) b3[threadIdx.x - 112] = b_h3[threadIdx.x - 112];

    const int node_l = threadIdx.x >> 4;        // 0..15: slot = node pair
    const int part   = threadIdx.x & 15;
    const int nA     = blockIdx.x * 32 + node_l;
    const int nB     = nA + 16;
    const bool actvA = (nA < n_nodes);
    const bool actvB = (nB < n_nodes);

    float4 h0A = make_float4(0.f, 0.f, 0.f, 0.f);
    float4 h0B = make_float4(0.f, 0.f, 0.f, 0.f);
    if (actvA) h0A = *(const float4*)&h0g[(size_t)nA * F + part * 4];
    if (actvB) h0B = *(const float4*)&h0g[(size_t)nB * F + part * 4];
    __syncthreads();

    float* rowAa = &actA[node_l * AP];
    float* rowAb = &actA[(node_l + 16) * AP];
    float* rowBa = &actB[node_l * AP];
    float* rowBb = &actB[(node_l + 16) * AP];
    *(float4*)&rowAa[part * 4] = h0A;
    *(float4*)&rowAb[part * 4] = h0B;

    // ---- layer 1: 64 -> 64, relu ----
    {
        float4 aA = *(const float4*)&bf[part * 4];
        float4 aB = aA;
#pragma unroll
        for (int k4 = 0; k4 < 16; ++k4) {
            float4 hA = *(const float4*)&rowAa[k4 * 4];
            float4 hB = *(const float4*)&rowAb[k4 * 4];
            float4 w0 = *(const float4*)&wf[(k4 * 4 + 0) * 64 + part * 4];
            float4 wq1 = *(const float4*)&wf[(k4 * 4 + 1) * 64 + part * 4];
            float4 wq2 = *(const float4*)&wf[(k4 * 4 + 2) * 64 + part * 4];
            float4 wq3 = *(const float4*)&wf[(k4 * 4 + 3) * 64 + part * 4];
            aA.x += hA.x * w0.x + hA.y * wq1.x + hA.z * wq2.x + hA.w * wq3.x;
            aA.y += hA.x * w0.y + hA.y * wq1.y + hA.z * wq2.y + hA.w * wq3.y;
            aA.z += hA.x * w0.z + hA.y * wq1.z + hA.z * wq2.z + hA.w * wq3.z;
            aA.w += hA.x * w0.w + hA.y * wq1.w + hA.z * wq2.w + hA.w * wq3.w;
            aB.x += hB.x * w0.x + hB.y * wq1.x + hB.z * wq2.x + hB.w * wq3.x;
            aB.y += hB.x * w0.y + hB.y * wq1.y + hB.z * wq2.y + hB.w * wq3.y;
            aB.z += hB.x * w0.z + hB.y * wq1.z + hB.z * wq2.z + hB.w * wq3.z;
            aB.w += hB.x * w0.w + hB.y * wq1.w + hB.z * wq2.w + hB.w * wq3.w;
        }
        aA.x = aA.x > 0.f ? aA.x : 0.f; aA.y = aA.y > 0.f ? aA.y : 0.f;
        aA.z = aA.z > 0.f ? aA.z : 0.f; aA.w = aA.w > 0.f ? aA.w : 0.f;
        aB.x = aB.x > 0.f ? aB.x : 0.f; aB.y = aB.y > 0.f ? aB.y : 0.f;
        aB.z = aB.z > 0.f ? aB.z : 0.f; aB.w = aB.w > 0.f ? aB.w : 0.f;
        *(float4*)&rowBa[part * 4] = aA;
        *(float4*)&rowBb[part * 4] = aB;
    }

    // ---- layer 2: 64 -> 32, relu ----
    {
        float axA = b1[part * 2], ayA = b1[part * 2 + 1];
        float axB = axA, ayB = ayA;
#pragma unroll
        for (int k4 = 0; k4 < 16; ++k4) {
            float4 hA = *(const float4*)&rowBa[k4 * 4];
            float4 hB = *(const float4*)&rowBb[k4 * 4];
            float2 wa = *(const float2*)&w1[(k4 * 4 + 0) * 32 + part * 2];
            float2 wb = *(const float2*)&w1[(k4 * 4 + 1) * 32 + part * 2];
            float2 wc = *(const float2*)&w1[(k4 * 4 + 2) * 32 + part * 2];
            float2 wd = *(const float2*)&w1[(k4 * 4 + 3) * 32 + part * 2];
            axA += hA.x * wa.x + hA.y * wb.x + hA.z * wc.x + hA.w * wd.x;
            ayA += hA.x * wa.y + hA.y * wb.y + hA.z * wc.y + hA.w * wd.y;
            axB += hB.x * wa.x + hB.y * wb.x + hB.z * wc.x + hB.w * wd.x;
            ayB += hB.x * wa.y + hB.y * wb.y + hB.z * wc.y + hB.w * wd.y;
        }
        axA = axA > 0.f ? axA : 0.f; ayA = ayA > 0.f ? ayA : 0.f;
        axB = axB > 0.f ? axB : 0.f; ayB = ayB > 0.f ? ayB : 0.f;
        float2 uA; uA.x = axA; uA.y = ayA;
        float2 uB; uB.x = axB; uB.y = ayB;
        *(float2*)&rowAa[part * 2] = uA;
        *(float2*)&rowAb[part * 2] = uB;
    }

    // ---- layer 3: 32 -> 16, relu ----
    {
        float aA = b2[part], aB = aA;
#pragma unroll
        for (int k4 = 0; k4 < 8; ++k4) {
            float4 hA = *(const float4*)&rowAa[k4 * 4];
            float4 hB = *(const float4*)&rowAb[k4 * 4];
            float w0 = w2[(k4 * 4 + 0) * 16 + part];
            float wq1 = w2[(k4 * 4 + 1) * 16 + part];
            float wq2 = w2[(k4 * 4 + 2) * 16 + part];
            float wq3 = w2[(k4 * 4 + 3) * 16 + part];
            aA += hA.x * w0 + hA.y * wq1 + hA.z * wq2 + hA.w * wq3;
            aB += hB.x * w0 + hB.y * wq1 + hB.z * wq2 + hB.w * wq3;
        }
        aA = aA > 0.f ? aA : 0.f;
        aB = aB > 0.f ? aB : 0.f;
        rowBa[part] = aA;
        rowBb[part] = aB;
    }

    // ---- layer 4: 16 -> 16, relu ----
    float rA, rB;
    {
        float aA = b3[part], aB = aA;
#pragma unroll
        for (int k4 = 0; k4 < 4; ++k4) {
            float4 hA = *(const float4*)&rowBa[k4 * 4];
            float4 hB = *(const float4*)&rowBb[k4 * 4];
            float w0 = w3[(k4 * 4 + 0) * 16 + part];
            float wq1 = w3[(k4 * 4 + 1) * 16 + part];
            float wq2 = w3[(k4 * 4 + 2) * 16 + part];
            float wq3 = w3[(k4 * 4 + 3) * 16 + part];
            aA += hA.x * w0 + hA.y * wq1 + hA.z * wq2 + hA.w * wq3;
            aB += hB.x * w0 + hB.y * wq1 + hB.z * wq2 + hB.w * wq3;
        }
        rA = aA > 0.f ? aA : 0.f;
        rB = aB > 0.f ? aB : 0.f;
    }

    if (actvA) rfeat[(size_t)nA * 16 + part] = rA;   // fully coalesced
    if (actvB) rfeat[(size_t)nB * 16 + part] = rB;
}

// ---------------------------------------------------------------------------
// Segmented mean-pool + both heads. One block per graph (batch is sorted).
// ---------------------------------------------------------------------------
__global__ void __launch_bounds__(256)
pool_head(const float* __restrict__ rfeat, const int* __restrict__ batch,
          const float* __restrict__ w_ev, const float* __restrict__ b_ev,
          const float* __restrict__ w_env, const float* __restrict__ b_env,
          float* __restrict__ out, int n_nodes, int n_graphs)
{
    __shared__ int s_bounds[2];
    __shared__ float partial[16][17];
    __shared__ float gvec[16];

    int g = blockIdx.x;
    if (threadIdx.x < 2) {
        int target = g + threadIdx.x;          // lower_bound(batch, target)
        int lo = 0, hi = n_nodes;
        while (lo < hi) { int m = (lo + hi) >> 1; if (batch[m] < target) lo = m + 1; else hi = m; }
        s_bounds[threadIdx.x] = lo;
    }
    __syncthreads();
    int start = s_bounds[0], end = s_bounds[1];

    const int c = threadIdx.x & 15;     // channel
    const int w = threadIdx.x >> 4;     // node stream
    float acc = 0.f;
    for (int i = start + w; i < end; i += 16)
        acc += rfeat[(size_t)i * 16 + c];
    partial[w][c] = acc;
    __syncthreads();

    if (threadIdx.x < 16) {
        float s = 0.f;
#pragma unroll
        for (int ww = 0; ww < 16; ++ww) s += partial[ww][threadIdx.x];
        float cnt = (float)(end - start);
        cnt = cnt > 1.f ? cnt : 1.f;
        gvec[threadIdx.x] = s / cnt;
    }
    __syncthreads();

    if (threadIdx.x < 3) {
        int j = threadIdx.x;
        float a = b_ev[j];
#pragma unroll
        for (int k = 0; k < 16; ++k) a += gvec[k] * w_ev[k * 3 + j];
        out[(size_t)g * 3 + j] = a;
    } else if (threadIdx.x < 6) {
        int j = threadIdx.x - 3;
        float a = b_env[j];
#pragma unroll
        for (int k = 0; k < 16; ++k) a += gvec[k] * w_env[k * 3 + j];
        out[(size_t)n_graphs * 3 + (size_t)g * 3 + j] = a;
    }
}

// ---------------------------------------------------------------------------
extern "C" void kernel_launch(void* const* d_in, const int* in_sizes, int n_in,
                              void* d_out, int out_size, void* d_ws, size_t ws_size,
                              hipStream_t stream)
{
    const float* x       = (const float*)d_in[0];
    const int*   ei      = (const int*)d_in[1];
    const int*   batch   = (const int*)d_in[2];
    const float* w_gat   = (const float*)d_in[4];
    const float* att_src = (const float*)d_in[5];
    const float* att_dst = (const float*)d_in[6];
    const float* b_gat   = (const float*)d_in[7];
    const float* w_fuse  = (const float*)d_in[8];
    const float* b_fuse  = (const float*)d_in[9];
    const float* w_h1    = (const float*)d_in[10];
    const float* b_h1    = (const float*)d_in[11];
    const float* w_h2    = (const float*)d_in[12];
    const float* b_h2    = (const float*)d_in[13];
    const float* w_h3    = (const float*)d_in[14];
    const float* b_h3    = (const float*)d_in[15];
    const float* w_ev    = (const float*)d_in[16];
    const float* b_ev    = (const float*)d_in[17];
    const float* w_env   = (const float*)d_in[18];
    const float* b_env   = (const float*)d_in[19];

    const int n_nodes  = in_sizes[0] / FIN;       // 100000
    const int E        = in_sizes[1] / 2;         // 3200000
    const int n_graphs = 256;
    const int nbuck    = (n_nodes + BMASK) >> BSHIFT;   // 782

    // Workspace layout (~62.5 MB). bucketData is its own region (bucket_agg
    // reads it while writing h0 -> no overlay).
    float* ws     = (float*)d_ws;
    __half* xh    = (__half*)ws;                          // n*64 halves
    float* h0     = ws   + (size_t)n_nodes * 32;          // n*64 fp32
    float* a_s    = h0   + (size_t)n_nodes * F;           // n*4
    float* a_d    = a_s  + (size_t)n_nodes * HEADS;       // n*4
    float* rfeat  = a_d  + (size_t)n_nodes * HEADS;       // n*16
    int*   bucketData = (int*)(rfeat + (size_t)n_nodes * 16);  // nbuck*BCAP (14.4MB)
    int*   gcount = bucketData + (size_t)nbuck * BCAP;    // nbuck

    hipMemsetAsync(gcount, 0, (size_t)nbuck * sizeof(int), stream);

    const int nbP = (n_nodes + 255) / 256;                     // 391
    const int nbB = (E + 256 * BIN_EPT - 1) / (256 * BIN_EPT); // 782

    prep_bin<<<nbP + nbB, 256, 0, stream>>>(
        x, w_gat, att_src, att_dst, xh, a_s, a_d,
        ei, E, nbuck, gcount, bucketData, n_nodes, nbP);

    bucket_agg<<<nbuck, 256, 0, stream>>>(
        bucketData, gcount, a_s, a_d, xh, b_gat, h0, n_nodes);

    mlp_pool2<<<(n_nodes + 31) / 32, 256, 0, stream>>>(
        h0, w_fuse, b_fuse, w_h1, b_h1, w_h2, b_h2, w_h3, b_h3,
        rfeat, n_nodes);

    pool_head<<<n_graphs, 256, 0, stream>>>(
        rfeat, batch, w_ev, b_ev, w_env, b_env, (float*)d_out, n_nodes, n_graphs);
}

// Round 11
// 348.821 us; speedup vs baseline: 4.9354x; 4.9354x over previous
//
#include <hip/hip_runtime.h>
#include <hip/hip_bf16.h>
#include <hip/hip_fp16.h>

// N=100000 nodes, F_in=20, 4 heads x 16 ch = 64, E=3.2M edges (+N self loops),
// 256 graphs. All fp32 in/out.
//
// R10: REVERT of R9's bucket_agg (wave-serial per-edge LDS-atomic aggregation
// collapsed memory-level parallelism: 155GB/s, 1542us). Back to the R8
// pipeline: prep_bin -> csr_build -> gat_gather (zero-LDS, 8 streams/wave,
// 12.5K waves oversubscribed, 3.3TB/s) -> mlp_pool2 -> pool_head.
// One tweak: BIN_EPT 16->8 (halves the per-thread serial atomic+store chain
// in binning, doubles wave pool for latency hiding).
#define FIN 20
#define HEADS 4
#define F 64
#define NEG_SLOPE 0.2f
#define AP 68        // activation row stride (floats)
#define BSHIFT 9     // 512 nodes per bucket
#define BMASK 511
#define BCAP 18432   // per-bucket edge capacity (mean 16384, +16 sigma)
#define MAXBUCK 256
#define BIN_EPT 8    // edges per thread in bin pass

// ---------------------------------------------------------------------------
// Fused kernel 1: blocks [0, nbP) do node_prep; blocks [nbP, nbP+nbB) bin
// edges by dst bucket. The two jobs are independent.
// ---------------------------------------------------------------------------
__global__ void __launch_bounds__(256)
prep_bin(const float* __restrict__ x,
         const float* __restrict__ w_gat,
         const float* __restrict__ att_src,
         const float* __restrict__ att_dst,
         __half* __restrict__ xh,
         float* __restrict__ a_s,
         float* __restrict__ a_d,
         const int* __restrict__ ei, int E, int nbuck,
         int* __restrict__ gcount, int* __restrict__ bucketData,
         int n_nodes, int nbP)
{
    if (blockIdx.x < nbP) {
        // ---------------- node_prep ----------------
        __shared__ __align__(16) float w[FIN * F];
        __shared__ float asrc[F];
        __shared__ float adst[F];
        for (int i = threadIdx.x; i < FIN * F; i += 256) w[i] = w_gat[i];
        if (threadIdx.x < F) {
            asrc[threadIdx.x] = att_src[threadIdx.x];
            adst[threadIdx.x] = att_dst[threadIdx.x];
        }
        __syncthreads();

        int n = blockIdx.x * 256 + threadIdx.x;
        if (n >= n_nodes) return;

        float xv[FIN];
#pragma unroll
        for (int q = 0; q < FIN / 4; ++q) {
            float4 x4 = *(const float4*)&x[(size_t)n * FIN + q * 4];
            xv[q * 4 + 0] = x4.x; xv[q * 4 + 1] = x4.y;
            xv[q * 4 + 2] = x4.z; xv[q * 4 + 3] = x4.w;
        }

        float as[HEADS] = {0.f, 0.f, 0.f, 0.f};
        float ad[HEADS] = {0.f, 0.f, 0.f, 0.f};

#pragma unroll
        for (int j4 = 0; j4 < F / 4; ++j4) {
            float4 acc = make_float4(0.f, 0.f, 0.f, 0.f);
#pragma unroll
            for (int k = 0; k < FIN; ++k) {
                float4 w4 = *(const float4*)&w[k * F + j4 * 4];
                acc.x += xv[k] * w4.x;
                acc.y += xv[k] * w4.y;
                acc.z += xv[k] * w4.z;
                acc.w += xv[k] * w4.w;
            }
            __half2 p0 = __floats2half2_rn(acc.x, acc.y);
            __half2 p1 = __floats2half2_rn(acc.z, acc.w);
            float2 st;
            ((__half2*)&st)[0] = p0;
            ((__half2*)&st)[1] = p1;
            *(float2*)&xh[(size_t)n * F + j4 * 4] = st;

            int h = j4 >> 2;
            int jb = j4 * 4;
            as[h] += acc.x * asrc[jb] + acc.y * asrc[jb + 1] + acc.z * asrc[jb + 2] + acc.w * asrc[jb + 3];
            ad[h] += acc.x * adst[jb] + acc.y * adst[jb + 1] + acc.z * adst[jb + 2] + acc.w * adst[jb + 3];
        }
#pragma unroll
        for (int h = 0; h < HEADS; ++h) {
            a_s[(size_t)n * HEADS + h] = as[h];
            a_d[(size_t)n * HEADS + h] = ad[h];
        }
    } else {
        // ---------------- bin_pass ----------------
        __shared__ int lcnt[MAXBUCK];
        __shared__ int lbase[MAXBUCK];
        for (int i = threadIdx.x; i < nbuck; i += 256) lcnt[i] = 0;
        __syncthreads();

        int base = (blockIdx.x - nbP) * (256 * BIN_EPT);
        int b_[BIN_EPT], w_[BIN_EPT];
#pragma unroll
        for (int j = 0; j < BIN_EPT; ++j) {
            int e = base + j * 256 + threadIdx.x;
            if (e < E) {
                int src = ei[e];
                int dst = ei[E + e];
                b_[j] = dst >> BSHIFT;
                w_[j] = ((dst & BMASK) << 17) | src;   // src < 2^17 (N=100000)
                atomicAdd(&lcnt[b_[j]], 1);
            } else b_[j] = -1;
        }
        __syncthreads();
        for (int i = threadIdx.x; i < nbuck; i += 256) {
            int c = lcnt[i];
            lbase[i] = c ? atomicAdd(&gcount[i], c) : 0;
            lcnt[i] = 0;
        }
        __syncthreads();
#pragma unroll
        for (int j = 0; j < BIN_EPT; ++j) {
            if (b_[j] >= 0) {
                int p = lbase[b_[j]] + atomicAdd(&lcnt[b_[j]], 1);
                if (p < BCAP) bucketData[(size_t)b_[j] * BCAP + p] = w_[j];
            }
        }
    }
}

// ---------------------------------------------------------------------------
// CSR build: one block per bucket. Computes its own base (reduce over
// gcount[0..b) + b*512 self-loop offset), LDS histogram + scan of the
// bucket's <=512 nodes, writes off[] coalesced, plants self loops, scatters
// real edges within the bucket's ~70KB L2-resident window.
// ---------------------------------------------------------------------------
__global__ void __launch_bounds__(256)
csr_build(const int* __restrict__ bucketData, const int* __restrict__ gcount,
          int* __restrict__ off, int* __restrict__ srcs,
          int n_nodes, int total_edges)
{
    __shared__ int hist[512];     // reused as per-node cursor after the scan
    __shared__ int psum[256];
    int b = blockIdx.x;
    int t = threadIdx.x;
    int cnt = gcount[b]; if (cnt > BCAP) cnt = BCAP;
    int node0 = b << BSHIFT;
    int nnode = n_nodes - node0; if (nnode > 512) nnode = 512;

    // ---- per-block prefix of gcount ----
    psum[t] = (t < b) ? gcount[t] : 0;       // nbuck <= 256
    __syncthreads();
    for (int d = 128; d > 0; d >>= 1) {
        if (t < d) psum[t] += psum[t + d];
        __syncthreads();
    }
    int base = psum[0] + node0;              // + node0: self loops of earlier buckets
    __syncthreads();                         // psum free for reuse
    if (b == 0 && t == 0) off[n_nodes] = total_edges;

    hist[t] = 0; hist[t + 256] = 0;
    __syncthreads();
    const int* bd = bucketData + (size_t)b * BCAP;
    for (int i = t; i < cnt; i += 256) atomicAdd(&hist[bd[i] >> 17], 1);
    __syncthreads();

    int i0 = 2 * t, i1 = 2 * t + 1;
    int v0 = (i0 < nnode) ? hist[i0] + 1 : 0;   // +1: self loop slot
    int v1 = (i1 < nnode) ? hist[i1] + 1 : 0;
    psum[t] = v0 + v1;
    __syncthreads();
    for (int d = 1; d < 256; d <<= 1) {
        int w = (t >= d) ? psum[t - d] : 0;
        __syncthreads();
        psum[t] += w;
        __syncthreads();
    }
    int ex = (t == 0) ? 0 : psum[t - 1];
    __syncthreads();                 // hist reads done; reuse as cursor
    if (i0 < nnode) {
        int o = base + ex;
        off[node0 + i0] = o;
        srcs[o] = node0 + i0;        // self loop first
        hist[i0] = o + 1;
    }
    if (i1 < nnode) {
        int o = base + ex + v0;
        off[node0 + i1] = o;
        srcs[o] = node0 + i1;
        hist[i1] = o + 1;
    }
    __syncthreads();
    for (int i = t; i < cnt; i += 256) {
        int w = bd[i];
        int p = atomicAdd(&hist[w >> 17], 1);
        srcs[p] = w & 0x1FFFF;
    }
}

// ---------------------------------------------------------------------------
// Gather: 8 lanes per node, branch-free clamped 8-edge chunks, no LDS.
// Writes h0 = acc/z + b_gat.
// ---------------------------------------------------------------------------
__global__ void __launch_bounds__(256)
gat_gather(const int* __restrict__ off,
           const int* __restrict__ srcs,
           const float* __restrict__ a_s,
           const float* __restrict__ a_d,
           const __half* __restrict__ xh,
           const float* __restrict__ b_gat,
           float* __restrict__ h0out,
           int n_nodes)
{
    int tid = blockIdx.x * 256 + threadIdx.x;
    int n = tid >> 3;
    int part = tid & 7;
    if (n >= n_nodes) return;
    const int h = part >> 1;
    const int g8 = (threadIdx.x & 63) >> 3;   // node slot within wave (0..7)

    int kb = off[n];
    int ke = off[n + 1];
    float adh = a_d[n * 4 + h];

    float acc[8] = {0.f, 0.f, 0.f, 0.f, 0.f, 0.f, 0.f, 0.f};
    float zacc = 0.f;

    for (int base = kb; base < ke; base += 8) {
        int idx = base + part;
        idx = idx < ke - 1 ? idx : ke - 1;       // clamp: always valid load
        int my_s = srcs[idx];
#pragma unroll
        for (int j = 0; j < 8; ++j) {
            int s = __shfl(my_s, g8 * 8 + j, 64);
            float l = a_s[s * 4 + h] + adh;
            l = l > 0.f ? l : NEG_SLOPE * l;
            float e = (base + j < ke) ? __expf(l) : 0.f;
            zacc += e;
            float4 raw = *(const float4*)&xh[(size_t)s * F + part * 8];  // 8 halves
            const __half2* hp = (const __half2*)&raw;
            float2 c0 = __half22float2(hp[0]);
            float2 c1 = __half22float2(hp[1]);
            float2 c2 = __half22float2(hp[2]);
            float2 c3 = __half22float2(hp[3]);
            acc[0] += e * c0.x; acc[1] += e * c0.y;
            acc[2] += e * c1.x; acc[3] += e * c1.y;
            acc[4] += e * c2.x; acc[5] += e * c2.y;
            acc[6] += e * c3.x; acc[7] += e * c3.y;
        }
    }

    float inv = 1.f / zacc;            // zacc > 0 always (self loop)
    float4 bg0 = *(const float4*)&b_gat[part * 8];
    float4 bg1 = *(const float4*)&b_gat[part * 8 + 4];
    float4 o0, o1;
    o0.x = acc[0] * inv + bg0.x; o0.y = acc[1] * inv + bg0.y;
    o0.z = acc[2] * inv + bg0.z; o0.w = acc[3] * inv + bg0.w;
    o1.x = acc[4] * inv + bg1.x; o1.y = acc[5] * inv + bg1.y;
    o1.z = acc[6] * inv + bg1.z; o1.w = acc[7] * inv + bg1.w;
    *(float4*)&h0out[(size_t)n * F + part * 8]     = o0;
    *(float4*)&h0out[(size_t)n * F + part * 8 + 4] = o1;
}

// ---------------------------------------------------------------------------
// MLP. 16 threads per node-PAIR (nodes n and n+16 of a 32-node block): each
// weight register load feeds both nodes' FMAs -> half the LDS weight traffic
// per node. Activations ping-pong through LDS (wave-synchronous).
// ---------------------------------------------------------------------------
__global__ void __launch_bounds__(256)
mlp_pool2(const float* __restrict__ h0g,
          const float* __restrict__ w_fuse, const float* __restrict__ b_fuse,
          const float* __restrict__ w_h1, const float* __restrict__ b_h1,
          const float* __restrict__ w_h2, const float* __restrict__ b_h2,
          const float* __restrict__ w_h3, const float* __restrict__ b_h3,
          float* __restrict__ rfeat,
          int n_nodes)
{
    __shared__ __align__(16) float wf[64 * 64];
    __shared__ __align__(16) float w1[64 * 32];
    __shared__ __align__(16) float w2[32 * 16];
    __shared__ __align__(16) float w3[16 * 16];
    __shared__ __align__(16) float bf[64];
    __shared__ __align__(16) float b1[32], b2[16], b3[16];
    __shared__ __align__(16) float actA[32 * AP];
    __shared__ __align__(16) float actB[32 * AP];

    for (int i = threadIdx.x; i < 64 * 64; i += 256) wf[i] = w_fuse[i];
    for (int i = threadIdx.x; i < 64 * 32; i += 256) w1[i] = w_h1[i];
    for (int i = threadIdx.x; i < 32 * 16; i += 256) w2[i] = w_h2[i];
    for (int i = threadIdx.x; i < 16 * 16; i += 256) w3[i] = w_h3[i];
    if (threadIdx.x < 64) bf[threadIdx.x] = b_fuse[threadIdx.x];
    else if (threadIdx.x < 96)  b1[threadIdx.x - 64] = b_h1[threadIdx.x - 64];
    else if (threadIdx.x < 112) b2[threadIdx.x - 96] = b_h2[threadIdx.x - 96];
    else if (threadIdx.x < 128) b3[threadIdx.x - 112] = b_h3[threadIdx.x - 112];

    const int node_l = threadIdx.x >> 4;        // 0..15: slot = node pair
    const int part   = threadIdx.x & 15;
    const int nA     = blockIdx.x * 32 + node_l;
    const int nB     = nA + 16;
    const bool actvA = (nA < n_nodes);
    const bool actvB = (nB < n_nodes);

    float4 h0A = make_float4(0.f, 0.f, 0.f, 0.f);
    float4 h0B = make_float4(0.f, 0.f, 0.f, 0.f);
    if (actvA) h0A = *(const float4*)&h0g[(size_t)nA * F + part * 4];
    if (actvB) h0B = *(const float4*)&h0g[(size_t)nB * F + part * 4];
    __syncthreads();

    float* rowAa = &actA[node_l * AP];
    float* rowAb = &actA[(node_l + 16) * AP];
    float* rowBa = &actB[node_l * AP];
    float* rowBb = &actB[(node_l + 16) * AP];
    *(float4*)&rowAa[part * 4] = h0A;
    *(float4*)&rowAb[part * 4] = h0B;

    // ---- layer 1: 64 -> 64, relu ----
    {
        float4 aA = *(const float4*)&bf[part * 4];
        float4 aB = aA;
#pragma unroll
        for (int k4 = 0; k4 < 16; ++k4) {
            float4 hA = *(const float4*)&rowAa[k4 * 4];
            float4 hB = *(const float4*)&rowAb[k4 * 4];
            float4 w0 = *(const float4*)&wf[(k4 * 4 + 0) * 64 + part * 4];
            float4 wq1 = *(const float4*)&wf[(k4 * 4 + 1) * 64 + part * 4];
            float4 wq2 = *(const float4*)&wf[(k4 * 4 + 2) * 64 + part * 4];
            float4 wq3 = *(const float4*)&wf[(k4 * 4 + 3) * 64 + part * 4];
            aA.x += hA.x * w0.x + hA.y * wq1.x + hA.z * wq2.x + hA.w * wq3.x;
            aA.y += hA.x * w0.y + hA.y * wq1.y + hA.z * wq2.y + hA.w * wq3.y;
            aA.z += hA.x * w0.z + hA.y * wq1.z + hA.z * wq2.z + hA.w * wq3.z;
            aA.w += hA.x * w0.w + hA.y * wq1.w + hA.z * wq2.w + hA.w * wq3.w;
            aB.x += hB.x * w0.x + hB.y * wq1.x + hB.z * wq2.x + hB.w * wq3.x;
            aB.y += hB.x * w0.y + hB.y * wq1.y + hB.z * wq2.y + hB.w * wq3.y;
            aB.z += hB.x * w0.z + hB.y * wq1.z + hB.z * wq2.z + hB.w * wq3.z;
            aB.w += hB.x * w0.w + hB.y * wq1.w + hB.z * wq2.w + hB.w * wq3.w;
        }
        aA.x = aA.x > 0.f ? aA.x : 0.f; aA.y = aA.y > 0.f ? aA.y : 0.f;
        aA.z = aA.z > 0.f ? aA.z : 0.f; aA.w = aA.w > 0.f ? aA.w : 0.f;
        aB.x = aB.x > 0.f ? aB.x : 0.f; aB.y = aB.y > 0.f ? aB.y : 0.f;
        aB.z = aB.z > 0.f ? aB.z : 0.f; aB.w = aB.w > 0.f ? aB.w : 0.f;
        *(float4*)&rowBa[part * 4] = aA;
        *(float4*)&rowBb[part * 4] = aB;
    }

    // ---- layer 2: 64 -> 32, relu ----
    {
        float axA = b1[part * 2], ayA = b1[part * 2 + 1];
        float axB = axA, ayB = ayA;
#pragma unroll
        for (int k4 = 0; k4 < 16; ++k4) {
            float4 hA = *(const float4*)&rowBa[k4 * 4];
            float4 hB = *(const float4*)&rowBb[k4 * 4];
            float2 wa = *(const float2*)&w1[(k4 * 4 + 0) * 32 + part * 2];
            float2 wb = *(const float2*)&w1[(k4 * 4 + 1) * 32 + part * 2];
            float2 wc = *(const float2*)&w1[(k4 * 4 + 2) * 32 + part * 2];
            float2 wd = *(const float2*)&w1[(k4 * 4 + 3) * 32 + part * 2];
            axA += hA.x * wa.x + hA.y * wb.x + hA.z * wc.x + hA.w * wd.x;
            ayA += hA.x * wa.y + hA.y * wb.y + hA.z * wc.y + hA.w * wd.y;
            axB += hB.x * wa.x + hB.y * wb.x + hB.z * wc.x + hB.w * wd.x;
            ayB += hB.x * wa.y + hB.y * wb.y + hB.z * wc.y + hB.w * wd.y;
        }
        axA = axA > 0.f ? axA : 0.f; ayA = ayA > 0.f ? ayA : 0.f;
        axB = axB > 0.f ? axB : 0.f; ayB = ayB > 0.f ? ayB : 0.f;
        float2 uA; uA.x = axA; uA.y = ayA;
        float2 uB; uB.x = axB; uB.y = ayB;
        *(float2*)&rowAa[part * 2] = uA;
        *(float2*)&rowAb[part * 2] = uB;
    }

    // ---- layer 3: 32 -> 16, relu ----
    {
        float aA = b2[part], aB = aA;
#pragma unroll
        for (int k4 = 0; k4 < 8; ++k4) {
            float4 hA = *(const float4*)&rowAa[k4 * 4];
            float4 hB = *(const float4*)&rowAb[k4 * 4];
            float w0 = w2[(k4 * 4 + 0) * 16 + part];
            float wq1 = w2[(k4 * 4 + 1) * 16 + part];
            float wq2 = w2[(k4 * 4 + 2) * 16 + part];
            float wq3 = w2[(k4 * 4 + 3) * 16 + part];
            aA += hA.x * w0 + hA.y * wq1 + hA.z * wq2 + hA.w * wq3;
            aB += hB.x * w0 + hB.y * wq1 + hB.z * wq2 + hB.w * wq3;
        }
        aA = aA > 0.f ? aA : 0.f;
        aB = aB > 0.f ? aB : 0.f;
        rowBa[part] = aA;
        rowBb[part] = aB;
    }

    // ---- layer 4: 16 -> 16, relu ----
    float rA, rB;
    {
        float aA = b3[part], aB = aA;
#pragma unroll
        for (int k4 = 0; k4 < 4; ++k4) {
            float4 hA = *(const float4*)&rowBa[k4 * 4];
            float4 hB = *(const float4*)&rowBb[k4 * 4];
            float w0 = w3[(k4 * 4 + 0) * 16 + part];
            float wq1 = w3[(k4 * 4 + 1) * 16 + part];
            float wq2 = w3[(k4 * 4 + 2) * 16 + part];
            float wq3 = w3[(k4 * 4 + 3) * 16 + part];
            aA += hA.x * w0 + hA.y * wq1 + hA.z * wq2 + hA.w * wq3;
            aB += hB.x * w0 + hB.y * wq1 + hB.z * wq2 + hB.w * wq3;
        }
        rA = aA > 0.f ? aA : 0.f;
        rB = aB > 0.f ? aB : 0.f;
    }

    if (actvA) rfeat[(size_t)nA * 16 + part] = rA;   // fully coalesced
    if (actvB) rfeat[(size_t)nB * 16 + part] = rB;
}

// ---------------------------------------------------------------------------
// Segmented mean-pool + both heads. One block per graph (batch is sorted).
// ---------------------------------------------------------------------------
__global__ void __launch_bounds__(256)
pool_head(const float* __restrict__ rfeat, const int* __restrict__ batch,
          const float* __restrict__ w_ev, const float* __restrict__ b_ev,
          const float* __restrict__ w_env, const float* __restrict__ b_env,
          float* __restrict__ out, int n_nodes, int n_graphs)
{
    __shared__ int s_bounds[2];
    __shared__ float partial[16][17];
    __shared__ float gvec[16];

    int g = blockIdx.x;
    if (threadIdx.x < 2) {
        int target = g + threadIdx.x;          // lower_bound(batch, target)
        int lo = 0, hi = n_nodes;
        while (lo < hi) { int m = (lo + hi) >> 1; if (batch[m] < target) lo = m + 1; else hi = m; }
        s_bounds[threadIdx.x] = lo;
    }
    __syncthreads();
    int start = s_bounds[0], end = s_bounds[1];

    const int c = threadIdx.x & 15;     // channel
    const int w = threadIdx.x >> 4;     // node stream
    float acc = 0.f;
    for (int i = start + w; i < end; i += 16)
        acc += rfeat[(size_t)i * 16 + c];
    partial[w][c] = acc;
    __syncthreads();

    if (threadIdx.x < 16) {
        float s = 0.f;
#pragma unroll
        for (int ww = 0; ww < 16; ++ww) s += partial[ww][threadIdx.x];
        float cnt = (float)(end - start);
        cnt = cnt > 1.f ? cnt : 1.f;
        gvec[threadIdx.x] = s / cnt;
    }
    __syncthreads();

    if (threadIdx.x < 3) {
        int j = threadIdx.x;
        float a = b_ev[j];
#pragma unroll
        for (int k = 0; k < 16; ++k) a += gvec[k] * w_ev[k * 3 + j];
        out[(size_t)g * 3 + j] = a;
    } else if (threadIdx.x < 6) {
        int j = threadIdx.x - 3;
        float a = b_env[j];
#pragma unroll
        for (int k = 0; k < 16; ++k) a += gvec[k] * w_env[k * 3 + j];
        out[(size_t)n_graphs * 3 + (size_t)g * 3 + j] = a;
    }
}

// ---------------------------------------------------------------------------
extern "C" void kernel_launch(void* const* d_in, const int* in_sizes, int n_in,
                              void* d_out, int out_size, void* d_ws, size_t ws_size,
                              hipStream_t stream)
{
    const float* x       = (const float*)d_in[0];
    const int*   ei      = (const int*)d_in[1];
    const int*   batch   = (const int*)d_in[2];
    const float* w_gat   = (const float*)d_in[4];
    const float* att_src = (const float*)d_in[5];
    const float* att_dst = (const float*)d_in[6];
    const float* b_gat   = (const float*)d_in[7];
    const float* w_fuse  = (const float*)d_in[8];
    const float* b_fuse  = (const float*)d_in[9];
    const float* w_h1    = (const float*)d_in[10];
    const float* b_h1    = (const float*)d_in[11];
    const float* w_h2    = (const float*)d_in[12];
    const float* b_h2    = (const float*)d_in[13];
    const float* w_h3    = (const float*)d_in[14];
    const float* b_h3    = (const float*)d_in[15];
    const float* w_ev    = (const float*)d_in[16];
    const float* b_ev    = (const float*)d_in[17];
    const float* w_env   = (const float*)d_in[18];
    const float* b_env   = (const float*)d_in[19];

    const int n_nodes  = in_sizes[0] / FIN;       // 100000
    const int E        = in_sizes[1] / 2;         // 3200000
    const int n_graphs = 256;
    const int total    = E + n_nodes;             // edges incl self loops
    const int nbuck    = (n_nodes + BMASK) >> BSHIFT;   // 196

    // Workspace layout (~62 MB). bucketData overlays h0: the CSR build is
    // fully done before gat_gather writes h0.
    float* ws     = (float*)d_ws;
    __half* xh    = (__half*)ws;                          // n*64 halves
    float* h0     = ws   + (size_t)n_nodes * 32;          // n*64 fp32
    float* a_s    = h0   + (size_t)n_nodes * F;           // n*4
    float* a_d    = a_s  + (size_t)n_nodes * HEADS;       // n*4
    float* rfeat  = a_d  + (size_t)n_nodes * HEADS;       // n*16
    int*   off    = (int*)(rfeat + (size_t)n_nodes * 16); // n+1
    int*   srcs   = off    + n_nodes + 1;                 // E+n
    int*   gcount = srcs   + total;                       // nbuck
    int*   bucketData = (int*)h0;                         // nbuck*BCAP (14.5MB < 25.6MB)

    hipMemsetAsync(gcount, 0, (size_t)nbuck * sizeof(int), stream);

    const int nbP = (n_nodes + 255) / 256;                     // 391
    const int nbB = (E + 256 * BIN_EPT - 1) / (256 * BIN_EPT); // 1563

    prep_bin<<<nbP + nbB, 256, 0, stream>>>(
        x, w_gat, att_src, att_dst, xh, a_s, a_d,
        ei, E, nbuck, gcount, bucketData, n_nodes, nbP);

    csr_build<<<nbuck, 256, 0, stream>>>(
        bucketData, gcount, off, srcs, n_nodes, total);

    // Gather: 8 lanes/node -> 32 nodes per 256-thread block.
    gat_gather<<<(n_nodes * 8 + 255) / 256, 256, 0, stream>>>(
        off, srcs, a_s, a_d, xh, b_gat, h0, n_nodes);

    mlp_pool2<<<(n_nodes + 31) / 32, 256, 0, stream>>>(
        h0, w_fuse, b_fuse, w_h1, b_h1, w_h2, b_h2, w_h3, b_h3,
        rfeat, n_nodes);

    pool_head<<<n_graphs, 256, 0, stream>>>(
        rfeat, batch, w_ev, b_ev, w_env, b_env, (float*)d_out, n_nodes, n_graphs);
}

// Round 12
// 321.404 us; speedup vs baseline: 5.3564x; 1.0853x over previous
//
#include <hip/hip_runtime.h>
#include <hip/hip_bf16.h>
#include <hip/hip_fp16.h>

// N=100000 nodes, F_in=20, 4 heads x 16 ch = 64, E=3.2M edges (+N self loops),
// 256 graphs. All fp32 in/out.
//
// R11: (a) BIN_EPT back to 16 — R10's 8 doubled per-block binning overhead
// (196-entry LDS zero + reservation atomics); measured +16us. (b) mlp_pool2
// weights wf/w1 stored fp16 in LDS: halves the dominant LDS weight-read
// bytes (reads are wave-broadcast, no conflict change); fp32 accumulate.
#define FIN 20
#define HEADS 4
#define F 64
#define NEG_SLOPE 0.2f
#define AP 68        // activation row stride (floats)
#define BSHIFT 9     // 512 nodes per bucket
#define BMASK 511
#define BCAP 18432   // per-bucket edge capacity (mean 16384, +16 sigma)
#define MAXBUCK 256
#define BIN_EPT 16   // edges per thread in bin pass (16 proven best, R9)

// ---------------------------------------------------------------------------
// Fused kernel 1: blocks [0, nbP) do node_prep; blocks [nbP, nbP+nbB) bin
// edges by dst bucket. The two jobs are independent.
// ---------------------------------------------------------------------------
__global__ void __launch_bounds__(256)
prep_bin(const float* __restrict__ x,
         const float* __restrict__ w_gat,
         const float* __restrict__ att_src,
         const float* __restrict__ att_dst,
         __half* __restrict__ xh,
         float* __restrict__ a_s,
         float* __restrict__ a_d,
         const int* __restrict__ ei, int E, int nbuck,
         int* __restrict__ gcount, int* __restrict__ bucketData,
         int n_nodes, int nbP)
{
    if (blockIdx.x < nbP) {
        // ---------------- node_prep ----------------
        __shared__ __align__(16) float w[FIN * F];
        __shared__ float asrc[F];
        __shared__ float adst[F];
        for (int i = threadIdx.x; i < FIN * F; i += 256) w[i] = w_gat[i];
        if (threadIdx.x < F) {
            asrc[threadIdx.x] = att_src[threadIdx.x];
            adst[threadIdx.x] = att_dst[threadIdx.x];
        }
        __syncthreads();

        int n = blockIdx.x * 256 + threadIdx.x;
        if (n >= n_nodes) return;

        float xv[FIN];
#pragma unroll
        for (int q = 0; q < FIN / 4; ++q) {
            float4 x4 = *(const float4*)&x[(size_t)n * FIN + q * 4];
            xv[q * 4 + 0] = x4.x; xv[q * 4 + 1] = x4.y;
            xv[q * 4 + 2] = x4.z; xv[q * 4 + 3] = x4.w;
        }

        float as[HEADS] = {0.f, 0.f, 0.f, 0.f};
        float ad[HEADS] = {0.f, 0.f, 0.f, 0.f};

#pragma unroll
        for (int j4 = 0; j4 < F / 4; ++j4) {
            float4 acc = make_float4(0.f, 0.f, 0.f, 0.f);
#pragma unroll
            for (int k = 0; k < FIN; ++k) {
                float4 w4 = *(const float4*)&w[k * F + j4 * 4];
                acc.x += xv[k] * w4.x;
                acc.y += xv[k] * w4.y;
                acc.z += xv[k] * w4.z;
                acc.w += xv[k] * w4.w;
            }
            __half2 p0 = __floats2half2_rn(acc.x, acc.y);
            __half2 p1 = __floats2half2_rn(acc.z, acc.w);
            float2 st;
            ((__half2*)&st)[0] = p0;
            ((__half2*)&st)[1] = p1;
            *(float2*)&xh[(size_t)n * F + j4 * 4] = st;

            int h = j4 >> 2;
            int jb = j4 * 4;
            as[h] += acc.x * asrc[jb] + acc.y * asrc[jb + 1] + acc.z * asrc[jb + 2] + acc.w * asrc[jb + 3];
            ad[h] += acc.x * adst[jb] + acc.y * adst[jb + 1] + acc.z * adst[jb + 2] + acc.w * adst[jb + 3];
        }
#pragma unroll
        for (int h = 0; h < HEADS; ++h) {
            a_s[(size_t)n * HEADS + h] = as[h];
            a_d[(size_t)n * HEADS + h] = ad[h];
        }
    } else {
        // ---------------- bin_pass ----------------
        __shared__ int lcnt[MAXBUCK];
        __shared__ int lbase[MAXBUCK];
        for (int i = threadIdx.x; i < nbuck; i += 256) lcnt[i] = 0;
        __syncthreads();

        int base = (blockIdx.x - nbP) * (256 * BIN_EPT);
        int b_[BIN_EPT], w_[BIN_EPT];
#pragma unroll
        for (int j = 0; j < BIN_EPT; ++j) {
            int e = base + j * 256 + threadIdx.x;
            if (e < E) {
                int src = ei[e];
                int dst = ei[E + e];
                b_[j] = dst >> BSHIFT;
                w_[j] = ((dst & BMASK) << 17) | src;   // src < 2^17 (N=100000)
                atomicAdd(&lcnt[b_[j]], 1);
            } else b_[j] = -1;
        }
        __syncthreads();
        for (int i = threadIdx.x; i < nbuck; i += 256) {
            int c = lcnt[i];
            lbase[i] = c ? atomicAdd(&gcount[i], c) : 0;
            lcnt[i] = 0;
        }
        __syncthreads();
#pragma unroll
        for (int j = 0; j < BIN_EPT; ++j) {
            if (b_[j] >= 0) {
                int p = lbase[b_[j]] + atomicAdd(&lcnt[b_[j]], 1);
                if (p < BCAP) bucketData[(size_t)b_[j] * BCAP + p] = w_[j];
            }
        }
    }
}

// ---------------------------------------------------------------------------
// CSR build: one block per bucket. Computes its own base (reduce over
// gcount[0..b) + b*512 self-loop offset), LDS histogram + scan of the
// bucket's <=512 nodes, writes off[] coalesced, plants self loops, scatters
// real edges within the bucket's ~70KB L2-resident window.
// ---------------------------------------------------------------------------
__global__ void __launch_bounds__(256)
csr_build(const int* __restrict__ bucketData, const int* __restrict__ gcount,
          int* __restrict__ off, int* __restrict__ srcs,
          int n_nodes, int total_edges)
{
    __shared__ int hist[512];     // reused as per-node cursor after the scan
    __shared__ int psum[256];
    int b = blockIdx.x;
    int t = threadIdx.x;
    int cnt = gcount[b]; if (cnt > BCAP) cnt = BCAP;
    int node0 = b << BSHIFT;
    int nnode = n_nodes - node0; if (nnode > 512) nnode = 512;

    // ---- per-block prefix of gcount ----
    psum[t] = (t < b) ? gcount[t] : 0;       // nbuck <= 256
    __syncthreads();
    for (int d = 128; d > 0; d >>= 1) {
        if (t < d) psum[t] += psum[t + d];
        __syncthreads();
    }
    int base = psum[0] + node0;              // + node0: self loops of earlier buckets
    __syncthreads();                         // psum free for reuse
    if (b == 0 && t == 0) off[n_nodes] = total_edges;

    hist[t] = 0; hist[t + 256] = 0;
    __syncthreads();
    const int* bd = bucketData + (size_t)b * BCAP;
    for (int i = t; i < cnt; i += 256) atomicAdd(&hist[bd[i] >> 17], 1);
    __syncthreads();

    int i0 = 2 * t, i1 = 2 * t + 1;
    int v0 = (i0 < nnode) ? hist[i0] + 1 : 0;   // +1: self loop slot
    int v1 = (i1 < nnode) ? hist[i1] + 1 : 0;
    psum[t] = v0 + v1;
    __syncthreads();
    for (int d = 1; d < 256; d <<= 1) {
        int w = (t >= d) ? psum[t - d] : 0;
        __syncthreads();
        psum[t] += w;
        __syncthreads();
    }
    int ex = (t == 0) ? 0 : psum[t - 1];
    __syncthreads();                 // hist reads done; reuse as cursor
    if (i0 < nnode) {
        int o = base + ex;
        off[node0 + i0] = o;
        srcs[o] = node0 + i0;        // self loop first
        hist[i0] = o + 1;
    }
    if (i1 < nnode) {
        int o = base + ex + v0;
        off[node0 + i1] = o;
        srcs[o] = node0 + i1;
        hist[i1] = o + 1;
    }
    __syncthreads();
    for (int i = t; i < cnt; i += 256) {
        int w = bd[i];
        int p = atomicAdd(&hist[w >> 17], 1);
        srcs[p] = w & 0x1FFFF;
    }
}

// ---------------------------------------------------------------------------
// Gather: 8 lanes per node, branch-free clamped 8-edge chunks, no LDS.
// Writes h0 = acc/z + b_gat.
// ---------------------------------------------------------------------------
__global__ void __launch_bounds__(256)
gat_gather(const int* __restrict__ off,
           const int* __restrict__ srcs,
           const float* __restrict__ a_s,
           const float* __restrict__ a_d,
           const __half* __restrict__ xh,
           const float* __restrict__ b_gat,
           float* __restrict__ h0out,
           int n_nodes)
{
    int tid = blockIdx.x * 256 + threadIdx.x;
    int n = tid >> 3;
    int part = tid & 7;
    if (n >= n_nodes) return;
    const int h = part >> 1;
    const int g8 = (threadIdx.x & 63) >> 3;   // node slot within wave (0..7)

    int kb = off[n];
    int ke = off[n + 1];
    float adh = a_d[n * 4 + h];

    float acc[8] = {0.f, 0.f, 0.f, 0.f, 0.f, 0.f, 0.f, 0.f};
    float zacc = 0.f;

    for (int base = kb; base < ke; base += 8) {
        int idx = base + part;
        idx = idx < ke - 1 ? idx : ke - 1;       // clamp: always valid load
        int my_s = srcs[idx];
#pragma unroll
        for (int j = 0; j < 8; ++j) {
            int s = __shfl(my_s, g8 * 8 + j, 64);
            float l = a_s[s * 4 + h] + adh;
            l = l > 0.f ? l : NEG_SLOPE * l;
            float e = (base + j < ke) ? __expf(l) : 0.f;
            zacc += e;
            float4 raw = *(const float4*)&xh[(size_t)s * F + part * 8];  // 8 halves
            const __half2* hp = (const __half2*)&raw;
            float2 c0 = __half22float2(hp[0]);
            float2 c1 = __half22float2(hp[1]);
            float2 c2 = __half22float2(hp[2]);
            float2 c3 = __half22float2(hp[3]);
            acc[0] += e * c0.x; acc[1] += e * c0.y;
            acc[2] += e * c1.x; acc[3] += e * c1.y;
            acc[4] += e * c2.x; acc[5] += e * c2.y;
            acc[6] += e * c3.x; acc[7] += e * c3.y;
        }
    }

    float inv = 1.f / zacc;            // zacc > 0 always (self loop)
    float4 bg0 = *(const float4*)&b_gat[part * 8];
    float4 bg1 = *(const float4*)&b_gat[part * 8 + 4];
    float4 o0, o1;
    o0.x = acc[0] * inv + bg0.x; o0.y = acc[1] * inv + bg0.y;
    o0.z = acc[2] * inv + bg0.z; o0.w = acc[3] * inv + bg0.w;
    o1.x = acc[4] * inv + bg1.x; o1.y = acc[5] * inv + bg1.y;
    o1.z = acc[6] * inv + bg1.z; o1.w = acc[7] * inv + bg1.w;
    *(float4*)&h0out[(size_t)n * F + part * 8]     = o0;
    *(float4*)&h0out[(size_t)n * F + part * 8 + 4] = o1;
}

// ---------------------------------------------------------------------------
// MLP. 16 threads per node-PAIR (nodes n and n+16 of a 32-node block).
// wf/w1 stored fp16 in LDS (halved weight-read bytes; reads are wave-
// broadcast so no conflicts); fp32 accumulate. Activations ping-pong via LDS.
// ---------------------------------------------------------------------------
__global__ void __launch_bounds__(256)
mlp_pool2(const float* __restrict__ h0g,
          const float* __restrict__ w_fuse, const float* __restrict__ b_fuse,
          const float* __restrict__ w_h1, const float* __restrict__ b_h1,
          const float* __restrict__ w_h2, const float* __restrict__ b_h2,
          const float* __restrict__ w_h3, const float* __restrict__ b_h3,
          float* __restrict__ rfeat,
          int n_nodes)
{
    __shared__ __align__(16) __half wfh[64 * 64];   // 8 KB
    __shared__ __align__(16) __half w1h[64 * 32];   // 4 KB
    __shared__ __align__(16) float w2[32 * 16];
    __shared__ __align__(16) float w3[16 * 16];
    __shared__ __align__(16) float bf[64];
    __shared__ __align__(16) float b1[32], b2[16], b3[16];
    __shared__ __align__(16) float actA[32 * AP];
    __shared__ __align__(16) float actB[32 * AP];

    for (int i = threadIdx.x; i < 64 * 64; i += 256) wfh[i] = __float2half(w_fuse[i]);
    for (int i = threadIdx.x; i < 64 * 32; i += 256) w1h[i] = __float2half(w_h1[i]);
    for (int i = threadIdx.x; i < 32 * 16; i += 256) w2[i] = w_h2[i];
    for (int i = threadIdx.x; i < 16 * 16; i += 256) w3[i] = w_h3[i];
    if (threadIdx.x < 64) bf[threadIdx.x] = b_fuse[threadIdx.x];
    else if (threadIdx.x < 96)  b1[threadIdx.x - 64] = b_h1[threadIdx.x - 64];
    else if (threadIdx.x < 112) b2[threadIdx.x - 96] = b_h2[threadIdx.x - 96];
    else if (threadIdx.x < 128) b3[threadIdx.x - 112] = b_h3[threadIdx.x - 112];

    const int node_l = threadIdx.x >> 4;        // 0..15: slot = node pair
    const int part   = threadIdx.x & 15;
    const int nA     = blockIdx.x * 32 + node_l;
    const int nB     = nA + 16;
    const bool actvA = (nA < n_nodes);
    const bool actvB = (nB < n_nodes);

    float4 h0A = make_float4(0.f, 0.f, 0.f, 0.f);
    float4 h0B = make_float4(0.f, 0.f, 0.f, 0.f);
    if (actvA) h0A = *(const float4*)&h0g[(size_t)nA * F + part * 4];
    if (actvB) h0B = *(const float4*)&h0g[(size_t)nB * F + part * 4];
    __syncthreads();

    float* rowAa = &actA[node_l * AP];
    float* rowAb = &actA[(node_l + 16) * AP];
    float* rowBa = &actB[node_l * AP];
    float* rowBb = &actB[(node_l + 16) * AP];
    *(float4*)&rowAa[part * 4] = h0A;
    *(float4*)&rowAb[part * 4] = h0B;

    // ---- layer 1: 64 -> 64, relu ----
    {
        float4 aA = *(const float4*)&bf[part * 4];
        float4 aB = aA;
#pragma unroll
        for (int k4 = 0; k4 < 16; ++k4) {
            float4 hA = *(const float4*)&rowAa[k4 * 4];
            float4 hB = *(const float4*)&rowAb[k4 * 4];
#pragma unroll
            for (int q = 0; q < 4; ++q) {
                const __half2* wp = (const __half2*)&wfh[(k4 * 4 + q) * 64 + part * 4];
                float2 wlo = __half22float2(wp[0]);
                float2 whi = __half22float2(wp[1]);
                float hva = (q == 0) ? hA.x : (q == 1) ? hA.y : (q == 2) ? hA.z : hA.w;
                float hvb = (q == 0) ? hB.x : (q == 1) ? hB.y : (q == 2) ? hB.z : hB.w;
                aA.x += hva * wlo.x; aA.y += hva * wlo.y;
                aA.z += hva * whi.x; aA.w += hva * whi.y;
                aB.x += hvb * wlo.x; aB.y += hvb * wlo.y;
                aB.z += hvb * whi.x; aB.w += hvb * whi.y;
            }
        }
        aA.x = aA.x > 0.f ? aA.x : 0.f; aA.y = aA.y > 0.f ? aA.y : 0.f;
        aA.z = aA.z > 0.f ? aA.z : 0.f; aA.w = aA.w > 0.f ? aA.w : 0.f;
        aB.x = aB.x > 0.f ? aB.x : 0.f; aB.y = aB.y > 0.f ? aB.y : 0.f;
        aB.z = aB.z > 0.f ? aB.z : 0.f; aB.w = aB.w > 0.f ? aB.w : 0.f;
        *(float4*)&rowBa[part * 4] = aA;
        *(float4*)&rowBb[part * 4] = aB;
    }

    // ---- layer 2: 64 -> 32, relu ----
    {
        float axA = b1[part * 2], ayA = b1[part * 2 + 1];
        float axB = axA, ayB = ayA;
#pragma unroll
        for (int k4 = 0; k4 < 16; ++k4) {
            float4 hA = *(const float4*)&rowBa[k4 * 4];
            float4 hB = *(const float4*)&rowBb[k4 * 4];
#pragma unroll
            for (int q = 0; q < 4; ++q) {
                float2 w2f = __half22float2(*(const __half2*)&w1h[(k4 * 4 + q) * 32 + part * 2]);
                float hva = (q == 0) ? hA.x : (q == 1) ? hA.y : (q == 2) ? hA.z : hA.w;
                float hvb = (q == 0) ? hB.x : (q == 1) ? hB.y : (q == 2) ? hB.z : hB.w;
                axA += hva * w2f.x; ayA += hva * w2f.y;
                axB += hvb * w2f.x; ayB += hvb * w2f.y;
            }
        }
        axA = axA > 0.f ? axA : 0.f; ayA = ayA > 0.f ? ayA : 0.f;
        axB = axB > 0.f ? axB : 0.f; ayB = ayB > 0.f ? ayB : 0.f;
        float2 uA; uA.x = axA; uA.y = ayA;
        float2 uB; uB.x = axB; uB.y = ayB;
        *(float2*)&rowAa[part * 2] = uA;
        *(float2*)&rowAb[part * 2] = uB;
    }

    // ---- layer 3: 32 -> 16, relu ----
    {
        float aA = b2[part], aB = aA;
#pragma unroll
        for (int k4 = 0; k4 < 8; ++k4) {
            float4 hA = *(const float4*)&rowAa[k4 * 4];
            float4 hB = *(const float4*)&rowAb[k4 * 4];
            float w0 = w2[(k4 * 4 + 0) * 16 + part];
            float wq1 = w2[(k4 * 4 + 1) * 16 + part];
            float wq2 = w2[(k4 * 4 + 2) * 16 + part];
            float wq3 = w2[(k4 * 4 + 3) * 16 + part];
            aA += hA.x * w0 + hA.y * wq1 + hA.z * wq2 + hA.w * wq3;
            aB += hB.x * w0 + hB.y * wq1 + hB.z * wq2 + hB.w * wq3;
        }
        aA = aA > 0.f ? aA : 0.f;
        aB = aB > 0.f ? aB : 0.f;
        rowBa[part] = aA;
        rowBb[part] = aB;
    }

    // ---- layer 4: 16 -> 16, relu ----
    float rA, rB;
    {
        float aA = b3[part], aB = aA;
#pragma unroll
        for (int k4 = 0; k4 < 4; ++k4) {
            float4 hA = *(const float4*)&rowBa[k4 * 4];
            float4 hB = *(const float4*)&rowBb[k4 * 4];
            float w0 = w3[(k4 * 4 + 0) * 16 + part];
            float wq1 = w3[(k4 * 4 + 1) * 16 + part];
            float wq2 = w3[(k4 * 4 + 2) * 16 + part];
            float wq3 = w3[(k4 * 4 + 3) * 16 + part];
            aA += hA.x * w0 + hA.y * wq1 + hA.z * wq2 + hA.w * wq3;
            aB += hB.x * w0 + hB.y * wq1 + hB.z * wq2 + hB.w * wq3;
        }
        rA = aA > 0.f ? aA : 0.f;
        rB = aB > 0.f ? aB : 0.f;
    }

    if (actvA) rfeat[(size_t)nA * 16 + part] = rA;   // fully coalesced
    if (actvB) rfeat[(size_t)nB * 16 + part] = rB;
}

// ---------------------------------------------------------------------------
// Segmented mean-pool + both heads. One block per graph (batch is sorted).
// ---------------------------------------------------------------------------
__global__ void __launch_bounds__(256)
pool_head(const float* __restrict__ rfeat, const int* __restrict__ batch,
          const float* __restrict__ w_ev, const float* __restrict__ b_ev,
          const float* __restrict__ w_env, const float* __restrict__ b_env,
          float* __restrict__ out, int n_nodes, int n_graphs)
{
    __shared__ int s_bounds[2];
    __shared__ float partial[16][17];
    __shared__ float gvec[16];

    int g = blockIdx.x;
    if (threadIdx.x < 2) {
        int target = g + threadIdx.x;          // lower_bound(batch, target)
        int lo = 0, hi = n_nodes;
        while (lo < hi) { int m = (lo + hi) >> 1; if (batch[m] < target) lo = m + 1; else hi = m; }
        s_bounds[threadIdx.x] = lo;
    }
    __syncthreads();
    int start = s_bounds[0], end = s_bounds[1];

    const int c = threadIdx.x & 15;     // channel
    const int w = threadIdx.x >> 4;     // node stream
    float acc = 0.f;
    for (int i = start + w; i < end; i += 16)
        acc += rfeat[(size_t)i * 16 + c];
    partial[w][c] = acc;
    __syncthreads();

    if (threadIdx.x < 16) {
        float s = 0.f;
#pragma unroll
        for (int ww = 0; ww < 16; ++ww) s += partial[ww][threadIdx.x];
        float cnt = (float)(end - start);
        cnt = cnt > 1.f ? cnt : 1.f;
        gvec[threadIdx.x] = s / cnt;
    }
    __syncthreads();

    if (threadIdx.x < 3) {
        int j = threadIdx.x;
        float a = b_ev[j];
#pragma unroll
        for (int k = 0; k < 16; ++k) a += gvec[k] * w_ev[k * 3 + j];
        out[(size_t)g * 3 + j] = a;
    } else if (threadIdx.x < 6) {
        int j = threadIdx.x - 3;
        float a = b_env[j];
#pragma unroll
        for (int k = 0; k < 16; ++k) a += gvec[k] * w_env[k * 3 + j];
        out[(size_t)n_graphs * 3 + (size_t)g * 3 + j] = a;
    }
}

// ---------------------------------------------------------------------------
extern "C" void kernel_launch(void* const* d_in, const int* in_sizes, int n_in,
                              void* d_out, int out_size, void* d_ws, size_t ws_size,
                              hipStream_t stream)
{
    const float* x       = (const float*)d_in[0];
    const int*   ei      = (const int*)d_in[1];
    const int*   batch   = (const int*)d_in[2];
    const float* w_gat   = (const float*)d_in[4];
    const float* att_src = (const float*)d_in[5];
    const float* att_dst = (const float*)d_in[6];
    const float* b_gat   = (const float*)d_in[7];
    const float* w_fuse  = (const float*)d_in[8];
    const float* b_fuse  = (const float*)d_in[9];
    const float* w_h1    = (const float*)d_in[10];
    const float* b_h1    = (const float*)d_in[11];
    const float* w_h2    = (const float*)d_in[12];
    const float* b_h2    = (const float*)d_in[13];
    const float* w_h3    = (const float*)d_in[14];
    const float* b_h3    = (const float*)d_in[15];
    const float* w_ev    = (const float*)d_in[16];
    const float* b_ev    = (const float*)d_in[17];
    const float* w_env   = (const float*)d_in[18];
    const float* b_env   = (const float*)d_in[19];

    const int n_nodes  = in_sizes[0] / FIN;       // 100000
    const int E        = in_sizes[1] / 2;         // 3200000
    const int n_graphs = 256;
    const int total    = E + n_nodes;             // edges incl self loops
    const int nbuck    = (n_nodes + BMASK) >> BSHIFT;   // 196

    // Workspace layout (~62 MB). bucketData overlays h0: the CSR build is
    // fully done before gat_gather writes h0.
    float* ws     = (float*)d_ws;
    __half* xh    = (__half*)ws;                          // n*64 halves
    float* h0     = ws   + (size_t)n_nodes * 32;          // n*64 fp32
    float* a_s    = h0   + (size_t)n_nodes * F;           // n*4
    float* a_d    = a_s  + (size_t)n_nodes * HEADS;       // n*4
    float* rfeat  = a_d  + (size_t)n_nodes * HEADS;       // n*16
    int*   off    = (int*)(rfeat + (size_t)n_nodes * 16); // n+1
    int*   srcs   = off    + n_nodes + 1;                 // E+n
    int*   gcount = srcs   + total;                       // nbuck
    int*   bucketData = (int*)h0;                         // nbuck*BCAP (14.5MB < 25.6MB)

    hipMemsetAsync(gcount, 0, (size_t)nbuck * sizeof(int), stream);

    const int nbP = (n_nodes + 255) / 256;                     // 391
    const int nbB = (E + 256 * BIN_EPT - 1) / (256 * BIN_EPT); // 782

    prep_bin<<<nbP + nbB, 256, 0, stream>>>(
        x, w_gat, att_src, att_dst, xh, a_s, a_d,
        ei, E, nbuck, gcount, bucketData, n_nodes, nbP);

    csr_build<<<nbuck, 256, 0, stream>>>(
        bucketData, gcount, off, srcs, n_nodes, total);

    // Gather: 8 lanes/node -> 32 nodes per 256-thread block.
    gat_gather<<<(n_nodes * 8 + 255) / 256, 256, 0, stream>>>(
        off, srcs, a_s, a_d, xh, b_gat, h0, n_nodes);

    mlp_pool2<<<(n_nodes + 31) / 32, 256, 0, stream>>>(
        h0, w_fuse, b_fuse, w_h1, b_h1, w_h2, b_h2, w_h3, b_h3,
        rfeat, n_nodes);

    pool_head<<<n_graphs, 256, 0, stream>>>(
        rfeat, batch, w_ev, b_ev, w_env, b_env, (float*)d_out, n_nodes, n_graphs);
}

// Round 13
// 316.824 us; speedup vs baseline: 5.4338x; 1.0145x over previous
//
#include <hip/hip_runtime.h>
#include <hip/hip_bf16.h>
#include <hip/hip_fp16.h>

// N=100000 nodes, F_in=20, 4 heads x 16 ch = 64, E=3.2M edges (+N self loops),
// 256 graphs. All fp32 in/out.
//
// R12: (a) gat_gather + mlp_pool2 fused: same 32-node/256-thread block shape;
// MLP VALU work overlaps other waves' gather stalls, h0 lives in LDS (51MB
// global traffic + 1 launch deleted). 33KB LDS -> 4 blocks/CU (16 waves, vs
// 20 measured unfused — acceptable). (b) BSHIFT 9->8: csr_build was latency-
// bound on 64-iter dependent chains at 196 blocks; now 32-iter at 391 blocks.
#define FIN 20
#define HEADS 4
#define F 64
#define NEG_SLOPE 0.2f
#define AP 68        // activation row stride (floats)
#define BSHIFT 8     // 256 nodes per bucket
#define BMASK 255
#define BCAP 9216    // per-bucket edge capacity (mean 8192, +11 sigma)
#define MAXBUCK 512
#define BIN_EPT 16   // edges per thread in bin pass (16 proven best, R9/R11)

// ---------------------------------------------------------------------------
// Fused kernel 1: blocks [0, nbP) do node_prep; blocks [nbP, nbP+nbB) bin
// edges by dst bucket. The two jobs are independent.
// ---------------------------------------------------------------------------
__global__ void __launch_bounds__(256)
prep_bin(const float* __restrict__ x,
         const float* __restrict__ w_gat,
         const float* __restrict__ att_src,
         const float* __restrict__ att_dst,
         __half* __restrict__ xh,
         float* __restrict__ a_s,
         float* __restrict__ a_d,
         const int* __restrict__ ei, int E, int nbuck,
         int* __restrict__ gcount, int* __restrict__ bucketData,
         int n_nodes, int nbP)
{
    if (blockIdx.x < nbP) {
        // ---------------- node_prep ----------------
        __shared__ __align__(16) float w[FIN * F];
        __shared__ float asrc[F];
        __shared__ float adst[F];
        for (int i = threadIdx.x; i < FIN * F; i += 256) w[i] = w_gat[i];
        if (threadIdx.x < F) {
            asrc[threadIdx.x] = att_src[threadIdx.x];
            adst[threadIdx.x] = att_dst[threadIdx.x];
        }
        __syncthreads();

        int n = blockIdx.x * 256 + threadIdx.x;
        if (n >= n_nodes) return;

        float xv[FIN];
#pragma unroll
        for (int q = 0; q < FIN / 4; ++q) {
            float4 x4 = *(const float4*)&x[(size_t)n * FIN + q * 4];
            xv[q * 4 + 0] = x4.x; xv[q * 4 + 1] = x4.y;
            xv[q * 4 + 2] = x4.z; xv[q * 4 + 3] = x4.w;
        }

        float as[HEADS] = {0.f, 0.f, 0.f, 0.f};
        float ad[HEADS] = {0.f, 0.f, 0.f, 0.f};

#pragma unroll
        for (int j4 = 0; j4 < F / 4; ++j4) {
            float4 acc = make_float4(0.f, 0.f, 0.f, 0.f);
#pragma unroll
            for (int k = 0; k < FIN; ++k) {
                float4 w4 = *(const float4*)&w[k * F + j4 * 4];
                acc.x += xv[k] * w4.x;
                acc.y += xv[k] * w4.y;
                acc.z += xv[k] * w4.z;
                acc.w += xv[k] * w4.w;
            }
            __half2 p0 = __floats2half2_rn(acc.x, acc.y);
            __half2 p1 = __floats2half2_rn(acc.z, acc.w);
            float2 st;
            ((__half2*)&st)[0] = p0;
            ((__half2*)&st)[1] = p1;
            *(float2*)&xh[(size_t)n * F + j4 * 4] = st;

            int h = j4 >> 2;
            int jb = j4 * 4;
            as[h] += acc.x * asrc[jb] + acc.y * asrc[jb + 1] + acc.z * asrc[jb + 2] + acc.w * asrc[jb + 3];
            ad[h] += acc.x * adst[jb] + acc.y * adst[jb + 1] + acc.z * adst[jb + 2] + acc.w * adst[jb + 3];
        }
#pragma unroll
        for (int h = 0; h < HEADS; ++h) {
            a_s[(size_t)n * HEADS + h] = as[h];
            a_d[(size_t)n * HEADS + h] = ad[h];
        }
    } else {
        // ---------------- bin_pass ----------------
        __shared__ int lcnt[MAXBUCK];
        __shared__ int lbase[MAXBUCK];
        for (int i = threadIdx.x; i < nbuck; i += 256) lcnt[i] = 0;
        __syncthreads();

        int base = (blockIdx.x - nbP) * (256 * BIN_EPT);
        int b_[BIN_EPT], w_[BIN_EPT];
#pragma unroll
        for (int j = 0; j < BIN_EPT; ++j) {
            int e = base + j * 256 + threadIdx.x;
            if (e < E) {
                int src = ei[e];
                int dst = ei[E + e];
                b_[j] = dst >> BSHIFT;
                w_[j] = ((dst & BMASK) << 17) | src;   // src < 2^17 (N=100000)
                atomicAdd(&lcnt[b_[j]], 1);
            } else b_[j] = -1;
        }
        __syncthreads();
        for (int i = threadIdx.x; i < nbuck; i += 256) {
            int c = lcnt[i];
            lbase[i] = c ? atomicAdd(&gcount[i], c) : 0;
            lcnt[i] = 0;
        }
        __syncthreads();
#pragma unroll
        for (int j = 0; j < BIN_EPT; ++j) {
            if (b_[j] >= 0) {
                int p = lbase[b_[j]] + atomicAdd(&lcnt[b_[j]], 1);
                if (p < BCAP) bucketData[(size_t)b_[j] * BCAP + p] = w_[j];
            }
        }
    }
}

// ---------------------------------------------------------------------------
// CSR build: one block per 256-node bucket. Per-block prefix over gcount,
// LDS histogram + scan (one node per thread), off[] coalesced, self loops
// planted, edges scattered within the bucket's L2-resident window.
// ---------------------------------------------------------------------------
__global__ void __launch_bounds__(256)
csr_build(const int* __restrict__ bucketData, const int* __restrict__ gcount,
          int* __restrict__ off, int* __restrict__ srcs,
          int n_nodes, int total_edges)
{
    __shared__ int hist[256];     // reused as per-node cursor after the scan
    __shared__ int psum[256];
    int b = blockIdx.x;
    int t = threadIdx.x;
    int cnt = gcount[b]; if (cnt > BCAP) cnt = BCAP;
    int node0 = b << BSHIFT;
    int nnode = n_nodes - node0; if (nnode > 256) nnode = 256;

    // ---- per-block prefix of gcount (nbuck may exceed 256: strided) ----
    int acc = 0;
    for (int i = t; i < b; i += 256) acc += gcount[i];
    psum[t] = acc;
    __syncthreads();
    for (int d = 128; d > 0; d >>= 1) {
        if (t < d) psum[t] += psum[t + d];
        __syncthreads();
    }
    int base = psum[0] + node0;              // + node0: self loops of earlier buckets
    __syncthreads();                         // psum free for reuse
    if (b == 0 && t == 0) off[n_nodes] = total_edges;

    hist[t] = 0;
    __syncthreads();
    const int* bd = bucketData + (size_t)b * BCAP;
    for (int i = t; i < cnt; i += 256) atomicAdd(&hist[bd[i] >> 17], 1);
    __syncthreads();

    int v = (t < nnode) ? hist[t] + 1 : 0;   // +1: self loop slot
    psum[t] = v;
    __syncthreads();
    for (int d = 1; d < 256; d <<= 1) {
        int w = (t >= d) ? psum[t - d] : 0;
        __syncthreads();
        psum[t] += w;
        __syncthreads();
    }
    int ex = (t == 0) ? 0 : psum[t - 1];
    __syncthreads();                 // hist reads done; reuse as cursor
    if (t < nnode) {
        int o = base + ex;
        off[node0 + t] = o;
        srcs[o] = node0 + t;         // self loop first
        hist[t] = o + 1;
    }
    __syncthreads();
    for (int i = t; i < cnt; i += 256) {
        int w = bd[i];
        int p = atomicAdd(&hist[w >> 17], 1);
        srcs[p] = w & 0x1FFFF;
    }
}

// ---------------------------------------------------------------------------
// Fused gather + MLP. 32 nodes per 256-thread block.
// Gather: 8 lanes/node, branch-free clamped 8-edge chunks -> h0 into LDS.
// MLP: 16 threads per node-PAIR, fp16 wf/w1, LDS act ping-pong -> rfeat.
// MLP VALU work overlaps other resident waves' gather memory stalls.
// ---------------------------------------------------------------------------
__global__ void __launch_bounds__(256)
gat_mlp(const int* __restrict__ off,
        const int* __restrict__ srcs,
        const float* __restrict__ a_s,
        const float* __restrict__ a_d,
        const __half* __restrict__ xh,
        const float* __restrict__ b_gat,
        const float* __restrict__ w_fuse, const float* __restrict__ b_fuse,
        const float* __restrict__ w_h1, const float* __restrict__ b_h1,
        const float* __restrict__ w_h2, const float* __restrict__ b_h2,
        const float* __restrict__ w_h3, const float* __restrict__ b_h3,
        float* __restrict__ rfeat,
        int n_nodes)
{
    __shared__ __align__(16) __half wfh[64 * 64];   // 8 KB
    __shared__ __align__(16) __half w1h[64 * 32];   // 4 KB
    __shared__ __align__(16) float w2[32 * 16];
    __shared__ __align__(16) float w3[16 * 16];
    __shared__ __align__(16) float bf[64];
    __shared__ __align__(16) float b1[32], b2[16], b3[16];
    __shared__ __align__(16) float actA[32 * AP];   // h0 buffer, then act ping
    __shared__ __align__(16) float actB[32 * AP];   // act pong

    // ---- stage weights (completes during the gather phase) ----
    for (int i = threadIdx.x; i < 64 * 64; i += 256) wfh[i] = __float2half(w_fuse[i]);
    for (int i = threadIdx.x; i < 64 * 32; i += 256) w1h[i] = __float2half(w_h1[i]);
    for (int i = threadIdx.x; i < 32 * 16; i += 256) w2[i] = w_h2[i];
    for (int i = threadIdx.x; i < 16 * 16; i += 256) w3[i] = w_h3[i];
    if (threadIdx.x < 64) bf[threadIdx.x] = b_fuse[threadIdx.x];
    else if (threadIdx.x < 96)  b1[threadIdx.x - 64] = b_h1[threadIdx.x - 64];
    else if (threadIdx.x < 112) b2[threadIdx.x - 96] = b_h2[threadIdx.x - 96];
    else if (threadIdx.x < 128) b3[threadIdx.x - 112] = b_h3[threadIdx.x - 112];

    // ---- gather phase: 8 lanes per node, 32 nodes per block ----
    {
        const int node_l2 = threadIdx.x >> 3;       // 0..31
        const int part = threadIdx.x & 7;
        const int n = blockIdx.x * 32 + node_l2;
        const int h = part >> 1;
        const int g8 = (threadIdx.x & 63) >> 3;     // 8-lane group within wave

        float acc[8] = {0.f, 0.f, 0.f, 0.f, 0.f, 0.f, 0.f, 0.f};
        float zacc = 0.f;
        bool active = (n < n_nodes);
        if (active) {
            int kb = off[n];
            int ke = off[n + 1];
            float adh = a_d[n * 4 + h];
            for (int base = kb; base < ke; base += 8) {
                int idx = base + part;
                idx = idx < ke - 1 ? idx : ke - 1;       // clamp: always valid
                int my_s = srcs[idx];
#pragma unroll
                for (int j = 0; j < 8; ++j) {
                    int s = __shfl(my_s, g8 * 8 + j, 64);
                    float l = a_s[s * 4 + h] + adh;
                    l = l > 0.f ? l : NEG_SLOPE * l;
                    float e = (base + j < ke) ? __expf(l) : 0.f;
                    zacc += e;
                    float4 raw = *(const float4*)&xh[(size_t)s * F + part * 8];
                    const __half2* hp = (const __half2*)&raw;
                    float2 c0 = __half22float2(hp[0]);
                    float2 c1 = __half22float2(hp[1]);
                    float2 c2 = __half22float2(hp[2]);
                    float2 c3 = __half22float2(hp[3]);
                    acc[0] += e * c0.x; acc[1] += e * c0.y;
                    acc[2] += e * c1.x; acc[3] += e * c1.y;
                    acc[4] += e * c2.x; acc[5] += e * c2.y;
                    acc[6] += e * c3.x; acc[7] += e * c3.y;
                }
            }
        }
        float inv = active ? (1.f / zacc) : 0.f;    // zacc>0 (self loop)
        float4 bg0 = *(const float4*)&b_gat[part * 8];
        float4 bg1 = *(const float4*)&b_gat[part * 8 + 4];
        float4 o0, o1;
        o0.x = acc[0] * inv + bg0.x; o0.y = acc[1] * inv + bg0.y;
        o0.z = acc[2] * inv + bg0.z; o0.w = acc[3] * inv + bg0.w;
        o1.x = acc[4] * inv + bg1.x; o1.y = acc[5] * inv + bg1.y;
        o1.z = acc[6] * inv + bg1.z; o1.w = acc[7] * inv + bg1.w;
        *(float4*)&actA[node_l2 * AP + part * 8]     = o0;
        *(float4*)&actA[node_l2 * AP + part * 8 + 4] = o1;
    }
    __syncthreads();   // h0 in actA; weight staging complete

    // ---- MLP phase: 16 threads per node pair ----
    const int node_l = threadIdx.x >> 4;        // 0..15
    const int part   = threadIdx.x & 15;
    const int nA     = blockIdx.x * 32 + node_l;
    const int nB     = nA + 16;
    const bool actvA = (nA < n_nodes);
    const bool actvB = (nB < n_nodes);

    float* rowAa = &actA[node_l * AP];
    float* rowAb = &actA[(node_l + 16) * AP];
    float* rowBa = &actB[node_l * AP];
    float* rowBb = &actB[(node_l + 16) * AP];

    // ---- layer 1: 64 -> 64, relu ----
    {
        float4 aA = *(const float4*)&bf[part * 4];
        float4 aB = aA;
#pragma unroll
        for (int k4 = 0; k4 < 16; ++k4) {
            float4 hA = *(const float4*)&rowAa[k4 * 4];
            float4 hB = *(const float4*)&rowAb[k4 * 4];
#pragma unroll
            for (int q = 0; q < 4; ++q) {
                const __half2* wp = (const __half2*)&wfh[(k4 * 4 + q) * 64 + part * 4];
                float2 wlo = __half22float2(wp[0]);
                float2 whi = __half22float2(wp[1]);
                float hva = (q == 0) ? hA.x : (q == 1) ? hA.y : (q == 2) ? hA.z : hA.w;
                float hvb = (q == 0) ? hB.x : (q == 1) ? hB.y : (q == 2) ? hB.z : hB.w;
                aA.x += hva * wlo.x; aA.y += hva * wlo.y;
                aA.z += hva * whi.x; aA.w += hva * whi.y;
                aB.x += hvb * wlo.x; aB.y += hvb * wlo.y;
                aB.z += hvb * whi.x; aB.w += hvb * whi.y;
            }
        }
        aA.x = aA.x > 0.f ? aA.x : 0.f; aA.y = aA.y > 0.f ? aA.y : 0.f;
        aA.z = aA.z > 0.f ? aA.z : 0.f; aA.w = aA.w > 0.f ? aA.w : 0.f;
        aB.x = aB.x > 0.f ? aB.x : 0.f; aB.y = aB.y > 0.f ? aB.y : 0.f;
        aB.z = aB.z > 0.f ? aB.z : 0.f; aB.w = aB.w > 0.f ? aB.w : 0.f;
        *(float4*)&rowBa[part * 4] = aA;
        *(float4*)&rowBb[part * 4] = aB;
    }

    // ---- layer 2: 64 -> 32, relu ----
    {
        float axA = b1[part * 2], ayA = b1[part * 2 + 1];
        float axB = axA, ayB = ayA;
#pragma unroll
        for (int k4 = 0; k4 < 16; ++k4) {
            float4 hA = *(const float4*)&rowBa[k4 * 4];
            float4 hB = *(const float4*)&rowBb[k4 * 4];
#pragma unroll
            for (int q = 0; q < 4; ++q) {
                float2 w2f = __half22float2(*(const __half2*)&w1h[(k4 * 4 + q) * 32 + part * 2]);
                float hva = (q == 0) ? hA.x : (q == 1) ? hA.y : (q == 2) ? hA.z : hA.w;
                float hvb = (q == 0) ? hB.x : (q == 1) ? hB.y : (q == 2) ? hB.z : hB.w;
                axA += hva * w2f.x; ayA += hva * w2f.y;
                axB += hvb * w2f.x; ayB += hvb * w2f.y;
            }
        }
        axA = axA > 0.f ? axA : 0.f; ayA = ayA > 0.f ? ayA : 0.f;
        axB = axB > 0.f ? axB : 0.f; ayB = ayB > 0.f ? ayB : 0.f;
        float2 uA; uA.x = axA; uA.y = ayA;
        float2 uB; uB.x = axB; uB.y = ayB;
        *(float2*)&rowAa[part * 2] = uA;
        *(float2*)&rowAb[part * 2] = uB;
    }

    // ---- layer 3: 32 -> 16, relu ----
    {
        float aA = b2[part], aB = aA;
#pragma unroll
        for (int k4 = 0; k4 < 8; ++k4) {
            float4 hA = *(const float4*)&rowAa[k4 * 4];
            float4 hB = *(const float4*)&rowAb[k4 * 4];
            float w0 = w2[(k4 * 4 + 0) * 16 + part];
            float wq1 = w2[(k4 * 4 + 1) * 16 + part];
            float wq2 = w2[(k4 * 4 + 2) * 16 + part];
            float wq3 = w2[(k4 * 4 + 3) * 16 + part];
            aA += hA.x * w0 + hA.y * wq1 + hA.z * wq2 + hA.w * wq3;
            aB += hB.x * w0 + hB.y * wq1 + hB.z * wq2 + hB.w * wq3;
        }
        aA = aA > 0.f ? aA : 0.f;
        aB = aB > 0.f ? aB : 0.f;
        rowBa[part] = aA;
        rowBb[part] = aB;
    }

    // ---- layer 4: 16 -> 16, relu ----
    float rA, rB;
    {
        float aA = b3[part], aB = aA;
#pragma unroll
        for (int k4 = 0; k4 < 4; ++k4) {
            float4 hA = *(const float4*)&rowBa[k4 * 4];
            float4 hB = *(const float4*)&rowBb[k4 * 4];
            float w0 = w3[(k4 * 4 + 0) * 16 + part];
            float wq1 = w3[(k4 * 4 + 1) * 16 + part];
            float wq2 = w3[(k4 * 4 + 2) * 16 + part];
            float wq3 = w3[(k4 * 4 + 3) * 16 + part];
            aA += hA.x * w0 + hA.y * wq1 + hA.z * wq2 + hA.w * wq3;
            aB += hB.x * w0 + hB.y * wq1 + hB.z * wq2 + hB.w * wq3;
        }
        rA = aA > 0.f ? aA : 0.f;
        rB = aB > 0.f ? aB : 0.f;
    }

    if (actvA) rfeat[(size_t)nA * 16 + part] = rA;   // fully coalesced
    if (actvB) rfeat[(size_t)nB * 16 + part] = rB;
}

// ---------------------------------------------------------------------------
// Segmented mean-pool + both heads. One block per graph (batch is sorted).
// ---------------------------------------------------------------------------
__global__ void __launch_bounds__(256)
pool_head(const float* __restrict__ rfeat, const int* __restrict__ batch,
          const float* __restrict__ w_ev, const float* __restrict__ b_ev,
          const float* __restrict__ w_env, const float* __restrict__ b_env,
          float* __restrict__ out, int n_nodes, int n_graphs)
{
    __shared__ int s_bounds[2];
    __shared__ float partial[16][17];
    __shared__ float gvec[16];

    int g = blockIdx.x;
    if (threadIdx.x < 2) {
        int target = g + threadIdx.x;          // lower_bound(batch, target)
        int lo = 0, hi = n_nodes;
        while (lo < hi) { int m = (lo + hi) >> 1; if (batch[m] < target) lo = m + 1; else hi = m; }
        s_bounds[threadIdx.x] = lo;
    }
    __syncthreads();
    int start = s_bounds[0], end = s_bounds[1];

    const int c = threadIdx.x & 15;     // channel
    const int w = threadIdx.x >> 4;     // node stream
    float acc = 0.f;
    for (int i = start + w; i < end; i += 16)
        acc += rfeat[(size_t)i * 16 + c];
    partial[w][c] = acc;
    __syncthreads();

    if (threadIdx.x < 16) {
        float s = 0.f;
#pragma unroll
        for (int ww = 0; ww < 16; ++ww) s += partial[ww][threadIdx.x];
        float cnt = (float)(end - start);
        cnt = cnt > 1.f ? cnt : 1.f;
        gvec[threadIdx.x] = s / cnt;
    }
    __syncthreads();

    if (threadIdx.x < 3) {
        int j = threadIdx.x;
        float a = b_ev[j];
#pragma unroll
        for (int k = 0; k < 16; ++k) a += gvec[k] * w_ev[k * 3 + j];
        out[(size_t)g * 3 + j] = a;
    } else if (threadIdx.x < 6) {
        int j = threadIdx.x - 3;
        float a = b_env[j];
#pragma unroll
        for (int k = 0; k < 16; ++k) a += gvec[k] * w_env[k * 3 + j];
        out[(size_t)n_graphs * 3 + (size_t)g * 3 + j] = a;
    }
}

// ---------------------------------------------------------------------------
extern "C" void kernel_launch(void* const* d_in, const int* in_sizes, int n_in,
                              void* d_out, int out_size, void* d_ws, size_t ws_size,
                              hipStream_t stream)
{
    const float* x       = (const float*)d_in[0];
    const int*   ei      = (const int*)d_in[1];
    const int*   batch   = (const int*)d_in[2];
    const float* w_gat   = (const float*)d_in[4];
    const float* att_src = (const float*)d_in[5];
    const float* att_dst = (const float*)d_in[6];
    const float* b_gat   = (const float*)d_in[7];
    const float* w_fuse  = (const float*)d_in[8];
    const float* b_fuse  = (const float*)d_in[9];
    const float* w_h1    = (const float*)d_in[10];
    const float* b_h1    = (const float*)d_in[11];
    const float* w_h2    = (const float*)d_in[12];
    const float* b_h2    = (const float*)d_in[13];
    const float* w_h3    = (const float*)d_in[14];
    const float* b_h3    = (const float*)d_in[15];
    const float* w_ev    = (const float*)d_in[16];
    const float* b_ev    = (const float*)d_in[17];
    const float* w_env   = (const float*)d_in[18];
    const float* b_env   = (const float*)d_in[19];

    const int n_nodes  = in_sizes[0] / FIN;       // 100000
    const int E        = in_sizes[1] / 2;         // 3200000
    const int n_graphs = 256;
    const int total    = E + n_nodes;             // edges incl self loops
    const int nbuck    = (n_nodes + BMASK) >> BSHIFT;   // 391

    // Workspace layout (~49 MB), no overlays (h0 now lives in LDS).
    float* ws     = (float*)d_ws;
    __half* xh    = (__half*)ws;                          // n*64 halves
    float* a_s    = ws   + (size_t)n_nodes * 32;          // n*4
    float* a_d    = a_s  + (size_t)n_nodes * HEADS;       // n*4
    float* rfeat  = a_d  + (size_t)n_nodes * HEADS;       // n*16
    int*   off    = (int*)(rfeat + (size_t)n_nodes * 16); // n+1
    int*   srcs   = off    + n_nodes + 1;                 // E+n
    int*   gcount = srcs   + total;                       // nbuck
    int*   bucketData = gcount + nbuck;                   // nbuck*BCAP (14.4MB)

    hipMemsetAsync(gcount, 0, (size_t)nbuck * sizeof(int), stream);

    const int nbP = (n_nodes + 255) / 256;                     // 391
    const int nbB = (E + 256 * BIN_EPT - 1) / (256 * BIN_EPT); // 782

    prep_bin<<<nbP + nbB, 256, 0, stream>>>(
        x, w_gat, att_src, att_dst, xh, a_s, a_d,
        ei, E, nbuck, gcount, bucketData, n_nodes, nbP);

    csr_build<<<nbuck, 256, 0, stream>>>(
        bucketData, gcount, off, srcs, n_nodes, total);

    gat_mlp<<<(n_nodes + 31) / 32, 256, 0, stream>>>(
        off, srcs, a_s, a_d, xh, b_gat,
        w_fuse, b_fuse, w_h1, b_h1, w_h2, b_h2, w_h3, b_h3,
        rfeat, n_nodes);

    pool_head<<<n_graphs, 256, 0, stream>>>(
        rfeat, batch, w_ev, b_ev, w_env, b_env, (float*)d_out, n_nodes, n_graphs);
}

// Round 14
// 305.039 us; speedup vs baseline: 5.6437x; 1.0386x over previous
//
#include <hip/hip_runtime.h>
#include <hip/hip_bf16.h>
#include <hip/hip_fp16.h>

// N=100000 nodes, F_in=20, 4 heads x 16 ch = 64, E=3.2M edges (+N self loops),
// 256 graphs. All fp32 in/out.
//
// R13: gat_mlp's 33KB LDS capped it at 4 blocks/CU (Occ 37%, gather HBM
// 1.95TB/s vs 3.3 unfused). The act ping-pong is unnecessary: within a
// 16-thread group, all of a layer's LDS reads complete (wave-lockstep +
// accumulator data dependency) before its writes, and groups touch only
// their own rows -> single in-place act buffer. LDS 33.2->24KB = 6 blocks/CU.
#define FIN 20
#define HEADS 4
#define F 64
#define NEG_SLOPE 0.2f
#define AP 68        // activation row stride (floats)
#define BSHIFT 8     // 256 nodes per bucket
#define BMASK 255
#define BCAP 9216    // per-bucket edge capacity (mean 8192, +11 sigma)
#define MAXBUCK 512
#define BIN_EPT 16   // edges per thread in bin pass (16 proven best, R9/R11)

// ---------------------------------------------------------------------------
// Fused kernel 1: blocks [0, nbP) do node_prep; blocks [nbP, nbP+nbB) bin
// edges by dst bucket. The two jobs are independent.
// ---------------------------------------------------------------------------
__global__ void __launch_bounds__(256)
prep_bin(const float* __restrict__ x,
         const float* __restrict__ w_gat,
         const float* __restrict__ att_src,
         const float* __restrict__ att_dst,
         __half* __restrict__ xh,
         float* __restrict__ a_s,
         float* __restrict__ a_d,
         const int* __restrict__ ei, int E, int nbuck,
         int* __restrict__ gcount, int* __restrict__ bucketData,
         int n_nodes, int nbP)
{
    if (blockIdx.x < nbP) {
        // ---------------- node_prep ----------------
        __shared__ __align__(16) float w[FIN * F];
        __shared__ float asrc[F];
        __shared__ float adst[F];
        for (int i = threadIdx.x; i < FIN * F; i += 256) w[i] = w_gat[i];
        if (threadIdx.x < F) {
            asrc[threadIdx.x] = att_src[threadIdx.x];
            adst[threadIdx.x] = att_dst[threadIdx.x];
        }
        __syncthreads();

        int n = blockIdx.x * 256 + threadIdx.x;
        if (n >= n_nodes) return;

        float xv[FIN];
#pragma unroll
        for (int q = 0; q < FIN / 4; ++q) {
            float4 x4 = *(const float4*)&x[(size_t)n * FIN + q * 4];
            xv[q * 4 + 0] = x4.x; xv[q * 4 + 1] = x4.y;
            xv[q * 4 + 2] = x4.z; xv[q * 4 + 3] = x4.w;
        }

        float as[HEADS] = {0.f, 0.f, 0.f, 0.f};
        float ad[HEADS] = {0.f, 0.f, 0.f, 0.f};

#pragma unroll
        for (int j4 = 0; j4 < F / 4; ++j4) {
            float4 acc = make_float4(0.f, 0.f, 0.f, 0.f);
#pragma unroll
            for (int k = 0; k < FIN; ++k) {
                float4 w4 = *(const float4*)&w[k * F + j4 * 4];
                acc.x += xv[k] * w4.x;
                acc.y += xv[k] * w4.y;
                acc.z += xv[k] * w4.z;
                acc.w += xv[k] * w4.w;
            }
            __half2 p0 = __floats2half2_rn(acc.x, acc.y);
            __half2 p1 = __floats2half2_rn(acc.z, acc.w);
            float2 st;
            ((__half2*)&st)[0] = p0;
            ((__half2*)&st)[1] = p1;
            *(float2*)&xh[(size_t)n * F + j4 * 4] = st;

            int h = j4 >> 2;
            int jb = j4 * 4;
            as[h] += acc.x * asrc[jb] + acc.y * asrc[jb + 1] + acc.z * asrc[jb + 2] + acc.w * asrc[jb + 3];
            ad[h] += acc.x * adst[jb] + acc.y * adst[jb + 1] + acc.z * adst[jb + 2] + acc.w * adst[jb + 3];
        }
#pragma unroll
        for (int h = 0; h < HEADS; ++h) {
            a_s[(size_t)n * HEADS + h] = as[h];
            a_d[(size_t)n * HEADS + h] = ad[h];
        }
    } else {
        // ---------------- bin_pass ----------------
        __shared__ int lcnt[MAXBUCK];
        __shared__ int lbase[MAXBUCK];
        for (int i = threadIdx.x; i < nbuck; i += 256) lcnt[i] = 0;
        __syncthreads();

        int base = (blockIdx.x - nbP) * (256 * BIN_EPT);
        int b_[BIN_EPT], w_[BIN_EPT];
#pragma unroll
        for (int j = 0; j < BIN_EPT; ++j) {
            int e = base + j * 256 + threadIdx.x;
            if (e < E) {
                int src = ei[e];
                int dst = ei[E + e];
                b_[j] = dst >> BSHIFT;
                w_[j] = ((dst & BMASK) << 17) | src;   // src < 2^17 (N=100000)
                atomicAdd(&lcnt[b_[j]], 1);
            } else b_[j] = -1;
        }
        __syncthreads();
        for (int i = threadIdx.x; i < nbuck; i += 256) {
            int c = lcnt[i];
            lbase[i] = c ? atomicAdd(&gcount[i], c) : 0;
            lcnt[i] = 0;
        }
        __syncthreads();
#pragma unroll
        for (int j = 0; j < BIN_EPT; ++j) {
            if (b_[j] >= 0) {
                int p = lbase[b_[j]] + atomicAdd(&lcnt[b_[j]], 1);
                if (p < BCAP) bucketData[(size_t)b_[j] * BCAP + p] = w_[j];
            }
        }
    }
}

// ---------------------------------------------------------------------------
// CSR build: one block per 256-node bucket. Per-block prefix over gcount,
// LDS histogram + scan (one node per thread), off[] coalesced, self loops
// planted, edges scattered within the bucket's L2-resident window.
// ---------------------------------------------------------------------------
__global__ void __launch_bounds__(256)
csr_build(const int* __restrict__ bucketData, const int* __restrict__ gcount,
          int* __restrict__ off, int* __restrict__ srcs,
          int n_nodes, int total_edges)
{
    __shared__ int hist[256];     // reused as per-node cursor after the scan
    __shared__ int psum[256];
    int b = blockIdx.x;
    int t = threadIdx.x;
    int cnt = gcount[b]; if (cnt > BCAP) cnt = BCAP;
    int node0 = b << BSHIFT;
    int nnode = n_nodes - node0; if (nnode > 256) nnode = 256;

    // ---- per-block prefix of gcount (nbuck may exceed 256: strided) ----
    int acc = 0;
    for (int i = t; i < b; i += 256) acc += gcount[i];
    psum[t] = acc;
    __syncthreads();
    for (int d = 128; d > 0; d >>= 1) {
        if (t < d) psum[t] += psum[t + d];
        __syncthreads();
    }
    int base = psum[0] + node0;              // + node0: self loops of earlier buckets
    __syncthreads();                         // psum free for reuse
    if (b == 0 && t == 0) off[n_nodes] = total_edges;

    hist[t] = 0;
    __syncthreads();
    const int* bd = bucketData + (size_t)b * BCAP;
    for (int i = t; i < cnt; i += 256) atomicAdd(&hist[bd[i] >> 17], 1);
    __syncthreads();

    int v = (t < nnode) ? hist[t] + 1 : 0;   // +1: self loop slot
    psum[t] = v;
    __syncthreads();
    for (int d = 1; d < 256; d <<= 1) {
        int w = (t >= d) ? psum[t - d] : 0;
        __syncthreads();
        psum[t] += w;
        __syncthreads();
    }
    int ex = (t == 0) ? 0 : psum[t - 1];
    __syncthreads();                 // hist reads done; reuse as cursor
    if (t < nnode) {
        int o = base + ex;
        off[node0 + t] = o;
        srcs[o] = node0 + t;         // self loop first
        hist[t] = o + 1;
    }
    __syncthreads();
    for (int i = t; i < cnt; i += 256) {
        int w = bd[i];
        int p = atomicAdd(&hist[w >> 17], 1);
        srcs[p] = w & 0x1FFFF;
    }
}

// ---------------------------------------------------------------------------
// Fused gather + MLP. 32 nodes per 256-thread block.
// Gather: 8 lanes/node, branch-free clamped 8-edge chunks -> h0 into LDS.
// MLP: 16 threads per node-PAIR, fp16 wf/w1, SINGLE in-place act buffer
// (wave-lockstep + data dependency make layer read-then-write race-free).
// 24KB LDS -> 6 blocks/CU.
// ---------------------------------------------------------------------------
__global__ void __launch_bounds__(256)
gat_mlp(const int* __restrict__ off,
        const int* __restrict__ srcs,
        const float* __restrict__ a_s,
        const float* __restrict__ a_d,
        const __half* __restrict__ xh,
        const float* __restrict__ b_gat,
        const float* __restrict__ w_fuse, const float* __restrict__ b_fuse,
        const float* __restrict__ w_h1, const float* __restrict__ b_h1,
        const float* __restrict__ w_h2, const float* __restrict__ b_h2,
        const float* __restrict__ w_h3, const float* __restrict__ b_h3,
        float* __restrict__ rfeat,
        int n_nodes)
{
    __shared__ __align__(16) __half wfh[64 * 64];   // 8 KB
    __shared__ __align__(16) __half w1h[64 * 32];   // 4 KB
    __shared__ __align__(16) float w2[32 * 16];
    __shared__ __align__(16) float w3[16 * 16];
    __shared__ __align__(16) float bf[64];
    __shared__ __align__(16) float b1[32], b2[16], b3[16];
    __shared__ __align__(16) float act[32 * AP];    // h0, then in-place acts

    // ---- stage weights (completes during the gather phase) ----
    for (int i = threadIdx.x; i < 64 * 64; i += 256) wfh[i] = __float2half(w_fuse[i]);
    for (int i = threadIdx.x; i < 64 * 32; i += 256) w1h[i] = __float2half(w_h1[i]);
    for (int i = threadIdx.x; i < 32 * 16; i += 256) w2[i] = w_h2[i];
    for (int i = threadIdx.x; i < 16 * 16; i += 256) w3[i] = w_h3[i];
    if (threadIdx.x < 64) bf[threadIdx.x] = b_fuse[threadIdx.x];
    else if (threadIdx.x < 96)  b1[threadIdx.x - 64] = b_h1[threadIdx.x - 64];
    else if (threadIdx.x < 112) b2[threadIdx.x - 96] = b_h2[threadIdx.x - 96];
    else if (threadIdx.x < 128) b3[threadIdx.x - 112] = b_h3[threadIdx.x - 112];

    // ---- gather phase: 8 lanes per node, 32 nodes per block ----
    {
        const int node_l2 = threadIdx.x >> 3;       // 0..31
        const int part = threadIdx.x & 7;
        const int n = blockIdx.x * 32 + node_l2;
        const int h = part >> 1;
        const int g8 = (threadIdx.x & 63) >> 3;     // 8-lane group within wave

        float acc[8] = {0.f, 0.f, 0.f, 0.f, 0.f, 0.f, 0.f, 0.f};
        float zacc = 0.f;
        bool active = (n < n_nodes);
        if (active) {
            int kb = off[n];
            int ke = off[n + 1];
            float adh = a_d[n * 4 + h];
            for (int base = kb; base < ke; base += 8) {
                int idx = base + part;
                idx = idx < ke - 1 ? idx : ke - 1;       // clamp: always valid
                int my_s = srcs[idx];
#pragma unroll
                for (int j = 0; j < 8; ++j) {
                    int s = __shfl(my_s, g8 * 8 + j, 64);
                    float l = a_s[s * 4 + h] + adh;
                    l = l > 0.f ? l : NEG_SLOPE * l;
                    float e = (base + j < ke) ? __expf(l) : 0.f;
                    zacc += e;
                    float4 raw = *(const float4*)&xh[(size_t)s * F + part * 8];
                    const __half2* hp = (const __half2*)&raw;
                    float2 c0 = __half22float2(hp[0]);
                    float2 c1 = __half22float2(hp[1]);
                    float2 c2 = __half22float2(hp[2]);
                    float2 c3 = __half22float2(hp[3]);
                    acc[0] += e * c0.x; acc[1] += e * c0.y;
                    acc[2] += e * c1.x; acc[3] += e * c1.y;
                    acc[4] += e * c2.x; acc[5] += e * c2.y;
                    acc[6] += e * c3.x; acc[7] += e * c3.y;
                }
            }
        }
        float inv = active ? (1.f / zacc) : 0.f;    // zacc>0 (self loop)
        float4 bg0 = *(const float4*)&b_gat[part * 8];
        float4 bg1 = *(const float4*)&b_gat[part * 8 + 4];
        float4 o0, o1;
        o0.x = acc[0] * inv + bg0.x; o0.y = acc[1] * inv + bg0.y;
        o0.z = acc[2] * inv + bg0.z; o0.w = acc[3] * inv + bg0.w;
        o1.x = acc[4] * inv + bg1.x; o1.y = acc[5] * inv + bg1.y;
        o1.z = acc[6] * inv + bg1.z; o1.w = acc[7] * inv + bg1.w;
        *(float4*)&act[node_l2 * AP + part * 8]     = o0;
        *(float4*)&act[node_l2 * AP + part * 8 + 4] = o1;
    }
    __syncthreads();   // h0 in act; weight staging complete

    // ---- MLP phase: 16 threads per node pair, in-place act rows ----
    const int node_l = threadIdx.x >> 4;        // 0..15
    const int part   = threadIdx.x & 15;
    const int nA     = blockIdx.x * 32 + node_l;
    const int nB     = nA + 16;
    const bool actvA = (nA < n_nodes);
    const bool actvB = (nB < n_nodes);

    float* rowA = &act[node_l * AP];
    float* rowB = &act[(node_l + 16) * AP];

    // ---- layer 1: 64 -> 64, relu (read all 64, then overwrite in place) ----
    {
        float4 aA = *(const float4*)&bf[part * 4];
        float4 aB = aA;
#pragma unroll
        for (int k4 = 0; k4 < 16; ++k4) {
            float4 hA = *(const float4*)&rowA[k4 * 4];
            float4 hB = *(const float4*)&rowB[k4 * 4];
#pragma unroll
            for (int q = 0; q < 4; ++q) {
                const __half2* wp = (const __half2*)&wfh[(k4 * 4 + q) * 64 + part * 4];
                float2 wlo = __half22float2(wp[0]);
                float2 whi = __half22float2(wp[1]);
                float hva = (q == 0) ? hA.x : (q == 1) ? hA.y : (q == 2) ? hA.z : hA.w;
                float hvb = (q == 0) ? hB.x : (q == 1) ? hB.y : (q == 2) ? hB.z : hB.w;
                aA.x += hva * wlo.x; aA.y += hva * wlo.y;
                aA.z += hva * whi.x; aA.w += hva * whi.y;
                aB.x += hvb * wlo.x; aB.y += hvb * wlo.y;
                aB.z += hvb * whi.x; aB.w += hvb * whi.y;
            }
        }
        aA.x = aA.x > 0.f ? aA.x : 0.f; aA.y = aA.y > 0.f ? aA.y : 0.f;
        aA.z = aA.z > 0.f ? aA.z : 0.f; aA.w = aA.w > 0.f ? aA.w : 0.f;
        aB.x = aB.x > 0.f ? aB.x : 0.f; aB.y = aB.y > 0.f ? aB.y : 0.f;
        aB.z = aB.z > 0.f ? aB.z : 0.f; aB.w = aB.w > 0.f ? aB.w : 0.f;
        *(float4*)&rowA[part * 4] = aA;       // in-place: reads done (lockstep)
        *(float4*)&rowB[part * 4] = aB;
    }

    // ---- layer 2: 64 -> 32, relu (reads cols 0..63, writes cols 0..31) ----
    {
        float axA = b1[part * 2], ayA = b1[part * 2 + 1];
        float axB = axA, ayB = ayA;
#pragma unroll
        for (int k4 = 0; k4 < 16; ++k4) {
            float4 hA = *(const float4*)&rowA[k4 * 4];
            float4 hB = *(const float4*)&rowB[k4 * 4];
#pragma unroll
            for (int q = 0; q < 4; ++q) {
                float2 w2f = __half22float2(*(const __half2*)&w1h[(k4 * 4 + q) * 32 + part * 2]);
                float hva = (q == 0) ? hA.x : (q == 1) ? hA.y : (q == 2) ? hA.z : hA.w;
                float hvb = (q == 0) ? hB.x : (q == 1) ? hB.y : (q == 2) ? hB.z : hB.w;
                axA += hva * w2f.x; ayA += hva * w2f.y;
                axB += hvb * w2f.x; ayB += hvb * w2f.y;
            }
        }
        axA = axA > 0.f ? axA : 0.f; ayA = ayA > 0.f ? ayA : 0.f;
        axB = axB > 0.f ? axB : 0.f; ayB = ayB > 0.f ? ayB : 0.f;
        float2 uA; uA.x = axA; uA.y = ayA;
        float2 uB; uB.x = axB; uB.y = ayB;
        *(float2*)&rowA[part * 2] = uA;
        *(float2*)&rowB[part * 2] = uB;
    }

    // ---- layer 3: 32 -> 16, relu (reads cols 0..31, writes cols 0..15) ----
    {
        float aA = b2[part], aB = aA;
#pragma unroll
        for (int k4 = 0; k4 < 8; ++k4) {
            float4 hA = *(const float4*)&rowA[k4 * 4];
            float4 hB = *(const float4*)&rowB[k4 * 4];
            float w0 = w2[(k4 * 4 + 0) * 16 + part];
            float wq1 = w2[(k4 * 4 + 1) * 16 + part];
            float wq2 = w2[(k4 * 4 + 2) * 16 + part];
            float wq3 = w2[(k4 * 4 + 3) * 16 + part];
            aA += hA.x * w0 + hA.y * wq1 + hA.z * wq2 + hA.w * wq3;
            aB += hB.x * w0 + hB.y * wq1 + hB.z * wq2 + hB.w * wq3;
        }
        aA = aA > 0.f ? aA : 0.f;
        aB = aB > 0.f ? aB : 0.f;
        rowA[part] = aA;
        rowB[part] = aB;
    }

    // ---- layer 4: 16 -> 16, relu ----
    float rA, rB;
    {
        float aA = b3[part], aB = aA;
#pragma unroll
        for (int k4 = 0; k4 < 4; ++k4) {
            float4 hA = *(const float4*)&rowA[k4 * 4];
            float4 hB = *(const float4*)&rowB[k4 * 4];
            float w0 = w3[(k4 * 4 + 0) * 16 + part];
            float wq1 = w3[(k4 * 4 + 1) * 16 + part];
            float wq2 = w3[(k4 * 4 + 2) * 16 + part];
            float wq3 = w3[(k4 * 4 + 3) * 16 + part];
            aA += hA.x * w0 + hA.y * wq1 + hA.z * wq2 + hA.w * wq3;
            aB += hB.x * w0 + hB.y * wq1 + hB.z * wq2 + hB.w * wq3;
        }
        rA = aA > 0.f ? aA : 0.f;
        rB = aB > 0.f ? aB : 0.f;
    }

    if (actvA) rfeat[(size_t)nA * 16 + part] = rA;   // fully coalesced
    if (actvB) rfeat[(size_t)nB * 16 + part] = rB;
}

// ---------------------------------------------------------------------------
// Segmented mean-pool + both heads. One block per graph (batch is sorted).
// ---------------------------------------------------------------------------
__global__ void __launch_bounds__(256)
pool_head(const float* __restrict__ rfeat, const int* __restrict__ batch,
          const float* __restrict__ w_ev, const float* __restrict__ b_ev,
          const float* __restrict__ w_env, const float* __restrict__ b_env,
          float* __restrict__ out, int n_nodes, int n_graphs)
{
    __shared__ int s_bounds[2];
    __shared__ float partial[16][17];
    __shared__ float gvec[16];

    int g = blockIdx.x;
    if (threadIdx.x < 2) {
        int target = g + threadIdx.x;          // lower_bound(batch, target)
        int lo = 0, hi = n_nodes;
        while (lo < hi) { int m = (lo + hi) >> 1; if (batch[m] < target) lo = m + 1; else hi = m; }
        s_bounds[threadIdx.x] = lo;
    }
    __syncthreads();
    int start = s_bounds[0], end = s_bounds[1];

    const int c = threadIdx.x & 15;     // channel
    const int w = threadIdx.x >> 4;     // node stream
    float acc = 0.f;
    for (int i = start + w; i < end; i += 16)
        acc += rfeat[(size_t)i * 16 + c];
    partial[w][c] = acc;
    __syncthreads();

    if (threadIdx.x < 16) {
        float s = 0.f;
#pragma unroll
        for (int ww = 0; ww < 16; ++ww) s += partial[ww][threadIdx.x];
        float cnt = (float)(end - start);
        cnt = cnt > 1.f ? cnt : 1.f;
        gvec[threadIdx.x] = s / cnt;
    }
    __syncthreads();

    if (threadIdx.x < 3) {
        int j = threadIdx.x;
        float a = b_ev[j];
#pragma unroll
        for (int k = 0; k < 16; ++k) a += gvec[k] * w_ev[k * 3 + j];
        out[(size_t)g * 3 + j] = a;
    } else if (threadIdx.x < 6) {
        int j = threadIdx.x - 3;
        float a = b_env[j];
#pragma unroll
        for (int k = 0; k < 16; ++k) a += gvec[k] * w_env[k * 3 + j];
        out[(size_t)n_graphs * 3 + (size_t)g * 3 + j] = a;
    }
}

// ---------------------------------------------------------------------------
extern "C" void kernel_launch(void* const* d_in, const int* in_sizes, int n_in,
                              void* d_out, int out_size, void* d_ws, size_t ws_size,
                              hipStream_t stream)
{
    const float* x       = (const float*)d_in[0];
    const int*   ei      = (const int*)d_in[1];
    const int*   batch   = (const int*)d_in[2];
    const float* w_gat   = (const float*)d_in[4];
    const float* att_src = (const float*)d_in[5];
    const float* att_dst = (const float*)d_in[6];
    const float* b_gat   = (const float*)d_in[7];
    const float* w_fuse  = (const float*)d_in[8];
    const float* b_fuse  = (const float*)d_in[9];
    const float* w_h1    = (const float*)d_in[10];
    const float* b_h1    = (const float*)d_in[11];
    const float* w_h2    = (const float*)d_in[12];
    const float* b_h2    = (const float*)d_in[13];
    const float* w_h3    = (const float*)d_in[14];
    const float* b_h3    = (const float*)d_in[15];
    const float* w_ev    = (const float*)d_in[16];
    const float* b_ev    = (const float*)d_in[17];
    const float* w_env   = (const float*)d_in[18];
    const float* b_env   = (const float*)d_in[19];

    const int n_nodes  = in_sizes[0] / FIN;       // 100000
    const int E        = in_sizes[1] / 2;         // 3200000
    const int n_graphs = 256;
    const int total    = E + n_nodes;             // edges incl self loops
    const int nbuck    = (n_nodes + BMASK) >> BSHIFT;   // 391

    // Workspace layout (~49 MB), no overlays (h0 lives in LDS).
    float* ws     = (float*)d_ws;
    __half* xh    = (__half*)ws;                          // n*64 halves
    float* a_s    = ws   + (size_t)n_nodes * 32;          // n*4
    float* a_d    = a_s  + (size_t)n_nodes * HEADS;       // n*4
    float* rfeat  = a_d  + (size_t)n_nodes * HEADS;       // n*16
    int*   off    = (int*)(rfeat + (size_t)n_nodes * 16); // n+1
    int*   srcs   = off    + n_nodes + 1;                 // E+n
    int*   gcount = srcs   + total;                       // nbuck
    int*   bucketData = gcount + nbuck;                   // nbuck*BCAP (14.4MB)

    hipMemsetAsync(gcount, 0, (size_t)nbuck * sizeof(int), stream);

    const int nbP = (n_nodes + 255) / 256;                     // 391
    const int nbB = (E + 256 * BIN_EPT - 1) / (256 * BIN_EPT); // 782

    prep_bin<<<nbP + nbB, 256, 0, stream>>>(
        x, w_gat, att_src, att_dst, xh, a_s, a_d,
        ei, E, nbuck, gcount, bucketData, n_nodes, nbP);

    csr_build<<<nbuck, 256, 0, stream>>>(
        bucketData, gcount, off, srcs, n_nodes, total);

    gat_mlp<<<(n_nodes + 31) / 32, 256, 0, stream>>>(
        off, srcs, a_s, a_d, xh, b_gat,
        w_fuse, b_fuse, w_h1, b_h1, w_h2, b_h2, w_h3, b_h3,
        rfeat, n_nodes);

    pool_head<<<n_graphs, 256, 0, stream>>>(
        rfeat, batch, w_ev, b_ev, w_env, b_env, (float*)d_out, n_nodes, n_graphs);
}